// Round 3
// baseline (312.170 us; speedup 1.0000x reference)
//
#include <hip/hip_runtime.h>
#include <hip/hip_bf16.h>
#include <hip/hip_fp16.h>
#include <stdint.h>

#define NN 100000
#define NT 2000000
#define HD 48
#define VS 64                     // vh row stride in halfs (128 B, line-aligned)
#define CAP 56                    // per-center bucket capacity; P(Poisson(20) >= 56) ~ 4e-10
#define NPB 16                    // nodes per node_kernel block
#define NBH ((NT + 255) / 256)
#define NB ((NN + 1023) / 1024)   // 98 scan blocks (fallback)

// ---- coarse-bin pipeline (primary path) ----
#define BINB 64                       // centers per coarse bin
#define NBIN ((NN + BINB - 1) / BINB) // 1563
#define BINCAP 1792                   // metas/bin cap: mean 1280, sigma 35.8 -> +14.3σ
#define CHK 8192                      // triples per binA block
#define NCHK ((NT + CHK - 1) / CHK)   // 245

// weight encoding: w = qw * (1.3/32767); real triples give qw in [25206,32767],
// qw = 0 encodes w = 0 exactly -> dummy (padding) metas contribute nothing.
#define WSCALE (1.3f / 32767.0f)
#define WQUANT (32767.0f / 1.3f)

typedef _Float16 hf2 __attribute__((ext_vector_type(2)));

__device__ __forceinline__ float b2f(__hip_bfloat16 x) { return __bfloat162float(x); }

// Load a "float tensor" element whose storage is bf16 (flag=1) or f32 (flag=0).
__device__ __forceinline__ float ldf(const void* p, long long i, int isbf16) {
    if (isbf16) return b2f(((const __hip_bfloat16*)p)[i]);
    return ((const float*)p)[i];
}

__device__ __forceinline__ hf2 habs2(hf2 x) {
    union { hf2 h; unsigned int u; } c; c.h = x; c.u &= 0x7FFF7FFFu; return c.h;
}
__device__ __forceinline__ hf2 splat2(float f) {
    hf2 r; r.x = (_Float16)f; r.y = (_Float16)f; return r;
}
union V4H { uint4 u; hf2 h[4]; };

// ---------------------------------------------------------------------------
// prep (9 blocks): self-probe dtypes, fold weights.
// wu1f[o][k] = Wu[o][k];  bf[o][k] = sum_j Wu[o][48+j] * W3[j][k]
// ---------------------------------------------------------------------------
__global__ __launch_bounds__(256) void prep_kernel(
        const unsigned int* __restrict__ hw, const unsigned int* __restrict__ iw,
        int* __restrict__ flags,
        const void* __restrict__ W3, const void* __restrict__ Wu,
        float* __restrict__ wu1f, float* __restrict__ bf) {
    __shared__ int cbf, cix;
    int tid = threadIdx.x;
    if (tid == 0) { cbf = 0; cix = 0; }
    __syncthreads();
    unsigned int e = (hw[tid] >> 7) & 0xff;       // exponent of low-half bf16
    if (e >= 90 && e <= 144) atomicAdd(&cbf, 1);
    if (blockIdx.x == 0 && iw[2 * tid + 1] == 0) atomicAdd(&cix, 1);
    __syncthreads();
    int fb = (cbf >= 192) ? 1 : 0;                // bf16 ~256 hits; f32 ~55
    if (blockIdx.x == 0 && tid == 0) {
        flags[0] = fb;
        flags[1] = (cix >= 255) ? 1 : 0;          // int64 high words all zero
    }
    int i = blockIdx.x * 256 + tid;
    if (i < HD * HD) {
        int o = i / HD, hh = i % HD;
        wu1f[i] = ldf(Wu, o * 2 * HD + hh, fb);
        float s = 0.f;
        #pragma unroll 8
        for (int k = 0; k < HD; ++k)
            s += ldf(Wu, o * 2 * HD + HD + k, fb) * ldf(W3, k * HD + hh, fb);
        bf[i] = s;
    }
}

// ---------------------------------------------------------------------------
// node: u[n]=Wu1*h[n] (fp16 stride-48), v[n]=M*h[n] (fp16 stride-64 = 128 B
// line-aligned rows, dims 48..63 zeroed so gathers are single-line and the
// dg=6,7 lanes read zeros). 16 nodes/block amortizes the 18.4 KB W broadcast.
// ---------------------------------------------------------------------------
__global__ __launch_bounds__(256) void node_kernel(
        const void* __restrict__ h, const int* __restrict__ flags,
        const float* __restrict__ wu1f, const float* __restrict__ bf,
        __half* __restrict__ uh, __half* __restrict__ vh) {
    __shared__ float Ws[HD * 49];
    __shared__ float Bs[HD * 49];
    __shared__ float hs[NPB * HD];
    int tid = threadIdx.x;
    int fb = flags[0];
    for (int i = tid; i < HD * HD; i += 256) {
        int o = i / HD, hh = i % HD;
        Ws[o * 49 + hh] = wu1f[i];
        Bs[o * 49 + hh] = bf[i];
    }
    int base = blockIdx.x * NPB;                  // NN % 16 == 0
    for (int i = tid; i < NPB * HD; i += 256)
        hs[i] = ldf(h, (long long)base * HD + i, fb);
    {   // zero the vh pad dims 48..63 (16 nodes x 16 dims = 256 slots)
        int ln = tid >> 4, o = HD + (tid & 15);
        vh[(size_t)(base + ln) * VS + o] = (__half)0.f;
    }
    __syncthreads();
    for (int i = tid; i < NPB * HD; i += 256) {
        int ln = i / HD, o = i - ln * HD;
        const float* hr = hs + ln * HD;
        const float* wr = Ws + o * 49;
        const float* br = Bs + o * 49;
        float su = 0.f, sv = 0.f;
        #pragma unroll
        for (int k = 0; k < HD; ++k) { float hv = hr[k]; su += wr[k] * hv; sv += br[k] * hv; }
        int n = base + ln;
        uh[(size_t)n * HD + o] = __float2half(su);
        vh[(size_t)n * VS + o] = __float2half(sv);
    }
}

// ---------------------------------------------------------------------------
// binA (primary): two-phase block-aggregated scatter into 1563 coarse bins.
// meta: x = n1 | qw15<<17 ; y = n2 | (c&63)<<17   (qw: see WSCALE)
// ---------------------------------------------------------------------------
__global__ __launch_bounds__(1024) void binA_kernel(
        const void* __restrict__ idxp,
        const void* __restrict__ d1p, const void* __restrict__ d2p,
        const int* __restrict__ flags, int* __restrict__ gcur,
        uint2* __restrict__ binned) {
    __shared__ int h1[NBIN];
    __shared__ int h2[NBIN];
    __shared__ int gb[NBIN];
    int tid = threadIdx.x;
    for (int i = tid; i < NBIN; i += 1024) { h1[i] = 0; h2[i] = 0; }
    __syncthreads();
    int t0 = blockIdx.x * CHK;
    int fb = flags[0], fi = flags[1];
    const int* qi = (const int*)idxp;             // int64: low words at even idx

    for (int i = 0; i < CHK; i += 1024) {         // phase 1: bin histogram
        int t = t0 + i + tid;
        if (t < NT) {
            int c = fi ? qi[6LL * t] : qi[3LL * t];
            atomicAdd(&h1[c >> 6], 1);
        }
    }
    __syncthreads();
    for (int b = tid; b < NBIN; b += 1024) {      // reserve contiguous runs
        int n = h1[b];
        gb[b] = n ? atomicAdd(&gcur[b << 5], n) : 0;
    }
    __syncthreads();
    for (int i = 0; i < CHK; i += 1024) {         // phase 2: rank + scatter
        int t = t0 + i + tid;
        if (t >= NT) continue;
        int c, n1, n2;
        if (fi) {
            c  = qi[6LL * t];
            n1 = qi[6LL * t + 2];
            n2 = qi[6LL * t + 4];
        } else {
            c  = qi[3LL * t];
            n1 = qi[3LL * t + 1];
            n2 = qi[3LL * t + 2];
        }
        float d1 = ldf(d1p, t, fb);
        float d2 = ldf(d2p, t, fb);
        float asym = fabsf(d1 - d2) / (fmaxf(d1, d2) + 1e-8f);
        unsigned int qw = (unsigned int)((1.0f + 0.3f * asym) * WQUANT + 0.5f);
        if (qw > 32767u) qw = 32767u;
        int b = c >> 6;
        int r = atomicAdd(&h2[b], 1);
        int pos = gb[b] + r;
        if (pos < BINCAP)
            binned[(size_t)b * BINCAP + pos] =
                make_uint2((unsigned int)n1 | (qw << 17),
                           (unsigned int)n2 | ((unsigned int)(c & 63) << 17));
    }
}

// ---------------------------------------------------------------------------
// bin_accum (primary): one block per 64-center bin. Coalesced read of the
// bin's metas, LDS-atomic scatter into per-center LDS buckets, pad each
// bucket to a multiple of 8 with zero metas (qw=0 -> w=0 -> contributes 0;
// dummies gather the hot row-0 line). Inner loop: 8 triples/trip, depth-1
// software pipeline with named double buffers (prefetch trip t+8's two
// gathers while computing trip t) -> 2 gathers always in flight, no
// validity selects. Fused residual + LayerNorm epilogue.
// LDS 36.6 KB, VGPR pinned <=64 via (512,8): 4 blocks/CU = 32 waves/CU.
// ---------------------------------------------------------------------------
__global__ __launch_bounds__(512, 8) void bin_accum_kernel(
        const void* __restrict__ h, const int* __restrict__ flags,
        const __half* __restrict__ uh, const __half* __restrict__ vh,
        const int* __restrict__ gcur, const uint2* __restrict__ binned,
        const void* __restrict__ gamma, const void* __restrict__ beta,
        void* __restrict__ out) {
    __shared__ uint2 buckets[BINB][64];           // 32768 B, <=56 slots used
    __shared__ int   cur[BINB];
    __shared__ float ucs[8][64];
    __shared__ float accs[8][HD];
    int tid = threadIdx.x, fb = flags[0];
    int bin = blockIdx.x;

    for (int i = tid; i < BINB; i += 512) cur[i] = 0;
    __syncthreads();

    int nm = gcur[bin << 5]; if (nm > BINCAP) nm = BINCAP;
    const uint2* bp = binned + (size_t)bin * BINCAP;
    for (int i = tid; i < nm; i += 512) {         // LDS bucket scatter
        uint2 m = bp[i];
        int cl = (m.y >> 17) & (BINB - 1);
        int r = atomicAdd(&cur[cl], 1);
        if (r < CAP) buckets[cl][r] = m;
    }
    __syncthreads();

    // clamp, pad to multiple of 8 with zero metas, pack m|mPad<<8 into cur.
    // tid 0..511 <-> (cl = tid>>3, k = tid&7): same wave as the compute wave
    // for cl, so no extra barrier needed after this (wave-local LDS order).
    {
        int cl = tid >> 3, k = tid & 7;
        int c0 = cur[cl];
        int m = (c0 > CAP) ? CAP : c0;
        int mP = (m + 7) & ~7;
        int j0 = m + k;
        if (j0 < mP) buckets[cl][j0] = make_uint2(0u, 0u);
        if (k == 0) cur[cl] = m | (mP << 8);
    }

    int wv = tid >> 6, lane = tid & 63;
    int s = lane >> 3, dg = lane & 7;
    const char* vb = (const char*)vh;
    size_t dgo = (size_t)dg * 16;
    float gv = (lane < HD) ? ldf(gamma, lane, fb) : 0.f;
    float bv = (lane < HD) ? ldf(beta, lane, fb) : 0.f;

#define LOADG(MA, MB, WW, T) {                                               \
        uint2 mc = buckets[cl][(T) + s];                                     \
        unsigned ca = mc.x & 0x1FFFFu, cb = mc.y & 0x1FFFFu;                 \
        WW = (float)(mc.x >> 17) * WSCALE;                                   \
        MA.u = *(const uint4*)(vb + (size_t)ca * 128 + dgo);                 \
        MB.u = *(const uint4*)(vb + (size_t)cb * 128 + dgo); }

#define COMPUTEG(MA, MB, WW) {                                               \
        hf2 aw = splat2(0.505f * WW), bw = splat2(0.495f * WW);              \
        _Pragma("unroll")                                                    \
        for (int j = 0; j < 4; ++j) {                                        \
            hf2 p = MA.h[j] + MB.h[j] + uc4[j];                              \
            hf2 acch = p * aw + habs2(p) * bw;                               \
            accf[2 * j]     += (float)acch.x;                                \
            accf[2 * j + 1] += (float)acch.y; } }

    for (int ci = 0; ci < BINB / 8; ++ci) {       // 8 centers per wave
        int cl = wv * (BINB / 8) + ci;
        int n = bin * BINB + cl;
        if (n >= NN) continue;                    // last bin: tail centers

        int raw = cur[cl];
        int m = raw & 255, mP = raw >> 8;
        float hval = (lane < HD) ? ldf(h, (long long)n * HD + lane, fb) : 0.f;
        float uval = (lane < HD) ? __half2float(uh[(size_t)n * HD + lane]) : 0.f;
        ucs[wv][lane] = uval;                     // wave-sync write->read
        hf2 uc4[4];
        #pragma unroll
        for (int j = 0; j < 4; ++j) {
            uc4[j].x = (_Float16)ucs[wv][dg * 8 + 2 * j];
            uc4[j].y = (_Float16)ucs[wv][dg * 8 + 2 * j + 1];
        }

        float accf[8] = {0.f, 0.f, 0.f, 0.f, 0.f, 0.f, 0.f, 0.f};
        if (mP) {
            V4H Xa, Xb, Ya, Yb;
            float wX = 0.f, wY = 0.f;
            LOADG(Xa, Xb, wX, 0);
            int cx = 1;
            for (int t = 0; t < mP; t += 8) {     // wave-uniform trip count
                int nxt = t + 8;
                if (cx) {
                    if (nxt < mP) LOADG(Ya, Yb, wY, nxt);
                    COMPUTEG(Xa, Xb, wX);
                } else {
                    if (nxt < mP) LOADG(Xa, Xb, wX, nxt);
                    COMPUTEG(Ya, Yb, wY);
                }
                cx ^= 1;
            }
        }

        // reduce across the 8 slot-copies (lane bits 3..5)
        #pragma unroll
        for (int j = 0; j < 8; ++j) {
            accf[j] += __shfl_xor(accf[j], 8, 64);
            accf[j] += __shfl_xor(accf[j], 16, 64);
            accf[j] += __shfl_xor(accf[j], 32, 64);
        }
        if (lane < 6) {                           // dims 0..47
            #pragma unroll
            for (int j = 0; j < 8; ++j) accs[wv][lane * 8 + j] = accf[j];
        }
        float av = (lane < HD) ? accs[wv][lane] : 0.f; // wave-sync

        float rnc = rsqrtf(fmaxf((float)m, 1.0f));
        float x = (lane < HD) ? (hval + av * rnc) : 0.f;
        float su = x, sq = x * x;
        #pragma unroll
        for (int o = 32; o; o >>= 1) {
            su += __shfl_xor(su, o, 64);
            sq += __shfl_xor(sq, o, 64);
        }
        float mu   = su * (1.0f / HD);
        float var  = sq * (1.0f / HD) - mu * mu;
        float rstd = rsqrtf(var + 1e-5f);
        if (lane < HD) {
            float r = (x - mu) * rstd * gv + bv;
            if (fb) ((__hip_bfloat16*)out)[(size_t)n * HD + lane] = __float2bfloat16(r);
            else    ((float*)out)[(size_t)n * HD + lane] = r;
        }
    }
#undef LOADG
#undef COMPUTEG
}

// ---------------------------------------------------------------------------
// hist (fallback only): line-padded counters cnt[c<<4].
// ---------------------------------------------------------------------------
__global__ __launch_bounds__(256) void hist_kernel(const void* __restrict__ idxp,
                                                   const int* __restrict__ flags,
                                                   int* __restrict__ cnt) {
    int t = blockIdx.x * 256 + threadIdx.x;
    if (t >= NT) return;
    int c = flags[1] ? (int)((const long long*)idxp)[3LL * t]
                     : ((const int*)idxp)[3 * t];
    atomicAdd(&cnt[c << 4], 1);
}

// ---------------------------------------------------------------------------
// scans (fallback only): exclusive scan of cnt[i<<4] -> off[NN].
// ---------------------------------------------------------------------------
__global__ __launch_bounds__(1024) void scan_part(const int* __restrict__ cnt,
                                                  int* __restrict__ off,
                                                  int* __restrict__ bsum) {
    __shared__ int wsums[16];
    int tid = threadIdx.x, lane = tid & 63, wv = tid >> 6;
    int i = blockIdx.x * 1024 + tid;
    int x = (i < NN) ? cnt[i << 4] : 0;
    int vx = x;
    #pragma unroll
    for (int o = 1; o < 64; o <<= 1) {
        int y = __shfl_up(vx, o, 64);
        if (lane >= o) vx += y;
    }
    if (lane == 63) wsums[wv] = vx;
    __syncthreads();
    if (tid == 0) {
        int s = 0;
        #pragma unroll
        for (int k = 0; k < 16; ++k) { int t2 = wsums[k]; wsums[k] = s; s += t2; }
        bsum[blockIdx.x] = s;
    }
    __syncthreads();
    if (i < NN) off[i] = wsums[wv] + vx - x;
}

__global__ __launch_bounds__(1024) void scan_add(int* __restrict__ off,
                                                 const int* __restrict__ bsum) {
    int bid = blockIdx.x;
    int pre = 0;
    for (int k = 0; k < bid; ++k) pre += bsum[k];
    int i = bid * 1024 + threadIdx.x;
    if (i < NN) off[i] += pre;
}

// ---------------------------------------------------------------------------
// scatter (fallback only): meta = uint2{ n1 | qw<<17, n2 }.
// pos = atomicAdd(&off[c],1)  (off -> inclusive end)
// ---------------------------------------------------------------------------
__global__ __launch_bounds__(256) void scatter_kernel(
        const void* __restrict__ idxp,
        const void* __restrict__ d1p, const void* __restrict__ d2p,
        const int* __restrict__ flags, int* __restrict__ cur,
        uint2* __restrict__ sp) {
    int t = blockIdx.x * 256 + threadIdx.x;
    if (t >= NT) return;
    int fb = flags[0];
    int c, n1, n2;
    if (flags[1]) {
        const long long* q = (const long long*)idxp;
        c = (int)q[3LL * t]; n1 = (int)q[3LL * t + 1]; n2 = (int)q[3LL * t + 2];
    } else {
        const int* q = (const int*)idxp;
        c = q[3 * t]; n1 = q[3 * t + 1]; n2 = q[3 * t + 2];
    }
    float d1 = ldf(d1p, t, fb);
    float d2 = ldf(d2p, t, fb);
    float asym = fabsf(d1 - d2) / (fmaxf(d1, d2) + 1e-8f);
    unsigned int qw = (unsigned int)((1.0f + 0.3f * asym) * WQUANT + 0.5f);
    if (qw > 32767u) qw = 32767u;
    uint2 m = make_uint2((unsigned int)n1 | (qw << 17), (unsigned int)n2);
    int pos = atomicAdd(&cur[c], 1);
    sp[pos] = m;
}

// ---------------------------------------------------------------------------
// accum (fallback only): one wave per center, segment from off[].
// ---------------------------------------------------------------------------
__global__ __launch_bounds__(256) void accum_kernel(
        const void* __restrict__ h, const int* __restrict__ flags,
        const __half* __restrict__ uh, const __half* __restrict__ vh,
        const int* __restrict__ seg, const uint2* __restrict__ sp,
        const void* __restrict__ gamma, const void* __restrict__ beta,
        void* __restrict__ out) {
    __shared__ uint2 metas[4][64];
    __shared__ float ucs[4][64];
    __shared__ float accs[4][HD];
    int tid = threadIdx.x, fb = flags[0];
    int wv = tid >> 6, lane = tid & 63;
    int n = blockIdx.x * 4 + wv;                  // NN % 4 == 0

    float hval = (lane < HD) ? ldf(h, (long long)n * HD + lane, fb) : 0.f;
    float uval = (lane < HD) ? __half2float(uh[(size_t)n * HD + lane]) : 0.f;
    ucs[wv][lane] = uval;                         // wave-sync write->read

    int s = lane >> 3, dg = lane & 7;
    hf2 uc4[4];
    #pragma unroll
    for (int j = 0; j < 4; ++j) {
        uc4[j].x = (_Float16)ucs[wv][dg * 8 + 2 * j];
        uc4[j].y = (_Float16)ucs[wv][dg * 8 + 2 * j + 1];
    }

    int start = (n == 0) ? 0 : seg[n - 1];
    int end = seg[n];
    float accf[8] = {0.f, 0.f, 0.f, 0.f, 0.f, 0.f, 0.f, 0.f};
    const char* vb = (const char*)vh;
    size_t dgo = (size_t)dg * 16;

    for (int chunk = start; chunk < end; chunk += 64) {
        int m = end - chunk; if (m > 64) m = 64;
        if (lane < m) metas[wv][lane] = sp[chunk + lane];
        for (int t = 0; t < m; t += 16) {
            uint2 m0 = metas[wv][t + s];
            uint2 m1 = metas[wv][t + 8 + s];
            int v0 = (t + s) < m, v1 = (t + 8 + s) < m;
            unsigned a0 = v0 ? (m0.x & 0x1FFFFu) : 0u;
            unsigned b0 = v0 ? (m0.y & 0x1FFFFu) : 0u;
            float w0 = v0 ? (float)(m0.x >> 17) * WSCALE : 0.f;
            unsigned a1 = v1 ? (m1.x & 0x1FFFFu) : 0u;
            unsigned b1 = v1 ? (m1.y & 0x1FFFFu) : 0u;
            float w1 = v1 ? (float)(m1.x >> 17) * WSCALE : 0.f;
            V4H pa0, pb0, pa1, pb1;
            pa0.u = *(const uint4*)(vb + (size_t)a0 * 128 + dgo);
            pb0.u = *(const uint4*)(vb + (size_t)b0 * 128 + dgo);
            pa1.u = *(const uint4*)(vb + (size_t)a1 * 128 + dgo);
            pb1.u = *(const uint4*)(vb + (size_t)b1 * 128 + dgo);
            hf2 aw0 = splat2(0.505f * w0), bw0 = splat2(0.495f * w0);
            hf2 aw1 = splat2(0.505f * w1), bw1 = splat2(0.495f * w1);
            #pragma unroll
            for (int j = 0; j < 4; ++j) {
                hf2 p0 = pa0.h[j] + pb0.h[j] + uc4[j];
                hf2 acch = p0 * aw0 + habs2(p0) * bw0;
                hf2 p1 = pa1.h[j] + pb1.h[j] + uc4[j];
                acch += p1 * aw1 + habs2(p1) * bw1;
                accf[2 * j]     += (float)acch.x;
                accf[2 * j + 1] += (float)acch.y;
            }
        }
    }

    #pragma unroll
    for (int j = 0; j < 8; ++j) {
        accf[j] += __shfl_xor(accf[j], 8, 64);
        accf[j] += __shfl_xor(accf[j], 16, 64);
        accf[j] += __shfl_xor(accf[j], 32, 64);
    }
    if (lane < 6) {
        #pragma unroll
        for (int j = 0; j < 8; ++j) accs[wv][lane * 8 + j] = accf[j];
    }
    float av = (lane < HD) ? accs[wv][lane] : 0.f;

    float rnc = rsqrtf(fmaxf((float)(end - start), 1.0f));
    float x = (lane < HD) ? (hval + av * rnc) : 0.f;
    float su = x, sq = x * x;
    #pragma unroll
    for (int o = 32; o; o >>= 1) {
        su += __shfl_xor(su, o, 64);
        sq += __shfl_xor(sq, o, 64);
    }
    float mu   = su * (1.0f / HD);
    float var  = sq * (1.0f / HD) - mu * mu;
    float rstd = rsqrtf(var + 1e-5f);
    if (lane < HD) {
        float g  = ldf(gamma, lane, fb);
        float bb = ldf(beta, lane, fb);
        float r = (x - mu) * rstd * g + bb;
        if (fb) ((__hip_bfloat16*)out)[(size_t)n * HD + lane] = __float2bfloat16(r);
        else    ((float*)out)[(size_t)n * HD + lane] = r;
    }
}

extern "C" void kernel_launch(void* const* d_in, const int* in_sizes, int n_in,
                              void* d_out, int out_size, void* d_ws, size_t ws_size,
                              hipStream_t stream) {
    const void* h     = d_in[0];
    const void* idx   = d_in[1];
    const void* d1    = d_in[2];
    const void* d2    = d_in[3];
    const void* W3    = d_in[4];
    const void* Wu    = d_in[5];
    const void* gamma = d_in[6];
    const void* beta  = d_in[7];

    char* base  = (char*)d_ws;
    int*   flags = (int*)base;                              // 64 B
    float* wu1f  = (float*)(base + 64);                     // 2304 f
    float* bf    = wu1f + HD * HD;                          // 2304 f
    uintptr_t ua = (uintptr_t)(bf + HD * HD);
    __half* uh   = (__half*)((ua + 127) & ~(uintptr_t)127); // NN*48 fp16 (9.6 MB)
    __half* vh   = (__half*)((char*)uh + (size_t)NN * HD * 2); // NN*64 fp16 (12.8 MB)
    char*  after = (char*)vh + (size_t)NN * VS * 2;

    // Primary (coarse-bin) layout: gcur + binned after vh.
    int*   gcur = (int*)after;                              // NBIN*32 ints (200 KB)
    uintptr_t bna = (uintptr_t)(gcur + (size_t)NBIN * 32);
    uint2* binned = (uint2*)((bna + 127) & ~(uintptr_t)127); // NBIN*BINCAP*8 = 22.4 MB
    size_t need_primary = ((char*)(binned + (size_t)NBIN * BINCAP)) - base;

    // Fallback layout: cnt/off/bsum/sp after vh (R8 pipeline).
    int*   cnt  = (int*)after;                              // NN*16 ints (6.4 MB)
    int*   off  = (int*)(cnt + (size_t)NN * 16);            // NN
    int*   bsum = off + NN;                                 // NB (+pad)
    uintptr_t spa = (uintptr_t)(bsum + 256);
    uint2* sp   = (uint2*)((spa + 15) & ~(uintptr_t)15);    // NT uint2 (16 MB)

    prep_kernel<<<(HD * HD + 255) / 256, 256, 0, stream>>>(
        (const unsigned int*)h, (const unsigned int*)idx, flags, W3, Wu, wu1f, bf);
    node_kernel<<<NN / NPB, 256, 0, stream>>>(h, flags, wu1f, bf, uh, vh);

    if (ws_size >= need_primary) {
        // ---- coarse-bin path: aggregated bin scatter + fused bucket/accum ----
        hipMemsetAsync(gcur, 0, (size_t)NBIN * 32 * sizeof(int), stream);
        binA_kernel<<<NCHK, 1024, 0, stream>>>(idx, d1, d2, flags, gcur, binned);
        bin_accum_kernel<<<NBIN, 512, 0, stream>>>(h, flags, uh, vh, gcur, binned,
                                                   gamma, beta, d_out);
    } else {
        // ---- fallback: hist + scan + sorted scatter (R8 pipeline) ----
        hipMemsetAsync(cnt, 0, (size_t)NN * 16 * sizeof(int), stream);
        hist_kernel<<<NBH, 256, 0, stream>>>(idx, flags, cnt);
        scan_part<<<NB, 1024, 0, stream>>>(cnt, off, bsum);
        scan_add<<<NB, 1024, 0, stream>>>(off, bsum);
        scatter_kernel<<<(NT + 255) / 256, 256, 0, stream>>>(
            idx, d1, d2, flags, off, sp);
        accum_kernel<<<NN / 4, 256, 0, stream>>>(h, flags, uh, vh, off, sp,
                                                 gamma, beta, d_out);
    }
}

// Round 5
// 275.517 us; speedup vs baseline: 1.1330x; 1.1330x over previous
//
#include <hip/hip_runtime.h>
#include <hip/hip_bf16.h>
#include <hip/hip_fp16.h>
#include <stdint.h>

#define NN 100000
#define NT 2000000
#define HD 48
#define VS 64                     // vh row stride in halfs (128 B, line-aligned)
#define CAP 56                    // per-center bucket capacity; P(Poisson(20) >= 56) ~ 4e-10
#define NPB 16                    // nodes per node_kernel block
#define NBH ((NT + 255) / 256)
#define NB ((NN + 1023) / 1024)   // 98 scan blocks (fallback)

// ---- coarse-bin pipeline (primary path) ----
#define BINB 64                       // centers per coarse bin
#define NBIN ((NN + BINB - 1) / BINB) // 1563
#define BINCAP 1792                   // metas/bin cap: mean 1280, sigma 35.8 -> +14.3σ
#define CHK 4096                      // triples per binA block
#define NCHK ((NT + CHK - 1) / CHK)   // 489
#define TPT (CHK / 1024)              // 4 triples per binA thread (reg-held)

// weight encoding: w = qw * (1.3/32767); real triples give qw in [25206,32767].
#define WSCALE (1.3f / 32767.0f)
#define WQUANT (32767.0f / 1.3f)

typedef _Float16 hf2 __attribute__((ext_vector_type(2)));

__device__ __forceinline__ float b2f(__hip_bfloat16 x) { return __bfloat162float(x); }

// Load a "float tensor" element whose storage is bf16 (flag=1) or f32 (flag=0).
__device__ __forceinline__ float ldf(const void* p, long long i, int isbf16) {
    if (isbf16) return b2f(((const __hip_bfloat16*)p)[i]);
    return ((const float*)p)[i];
}

__device__ __forceinline__ hf2 habs2(hf2 x) {
    union { hf2 h; unsigned int u; } c; c.h = x; c.u &= 0x7FFF7FFFu; return c.h;
}
__device__ __forceinline__ hf2 splat2(float f) {
    hf2 r; r.x = (_Float16)f; r.y = (_Float16)f; return r;
}
union V4H { uint4 u; hf2 h[4]; };

// ---------------------------------------------------------------------------
// prep (9 blocks): self-probe dtypes, fold weights.
// wu1f[o][k] = Wu[o][k];  bf[o][k] = sum_j Wu[o][48+j] * W3[j][k]
// ---------------------------------------------------------------------------
__global__ __launch_bounds__(256) void prep_kernel(
        const unsigned int* __restrict__ hw, const unsigned int* __restrict__ iw,
        int* __restrict__ flags,
        const void* __restrict__ W3, const void* __restrict__ Wu,
        float* __restrict__ wu1f, float* __restrict__ bf) {
    __shared__ int cbf, cix;
    int tid = threadIdx.x;
    if (tid == 0) { cbf = 0; cix = 0; }
    __syncthreads();
    unsigned int e = (hw[tid] >> 7) & 0xff;       // exponent of low-half bf16
    if (e >= 90 && e <= 144) atomicAdd(&cbf, 1);
    if (blockIdx.x == 0 && iw[2 * tid + 1] == 0) atomicAdd(&cix, 1);
    __syncthreads();
    int fb = (cbf >= 192) ? 1 : 0;                // bf16 ~256 hits; f32 ~55
    if (blockIdx.x == 0 && tid == 0) {
        flags[0] = fb;
        flags[1] = (cix >= 255) ? 1 : 0;          // int64 high words all zero
    }
    int i = blockIdx.x * 256 + tid;
    if (i < HD * HD) {
        int o = i / HD, hh = i % HD;
        wu1f[i] = ldf(Wu, o * 2 * HD + hh, fb);
        float s = 0.f;
        #pragma unroll 8
        for (int k = 0; k < HD; ++k)
            s += ldf(Wu, o * 2 * HD + HD + k, fb) * ldf(W3, k * HD + hh, fb);
        bf[i] = s;
    }
}

// ---------------------------------------------------------------------------
// node: u[n]=Wu1*h[n] (fp16 stride-48), v[n]=M*h[n] (fp16 stride-64 = 128 B
// line-aligned rows, dims 48..63 zeroed so gathers are single-line and the
// dg=6,7 lanes read zeros). 16 nodes/block amortizes the 18.4 KB W broadcast.
// ---------------------------------------------------------------------------
__global__ __launch_bounds__(256) void node_kernel(
        const void* __restrict__ h, const int* __restrict__ flags,
        const float* __restrict__ wu1f, const float* __restrict__ bf,
        __half* __restrict__ uh, __half* __restrict__ vh) {
    __shared__ float Ws[HD * 49];
    __shared__ float Bs[HD * 49];
    __shared__ float hs[NPB * HD];
    int tid = threadIdx.x;
    int fb = flags[0];
    for (int i = tid; i < HD * HD; i += 256) {
        int o = i / HD, hh = i % HD;
        Ws[o * 49 + hh] = wu1f[i];
        Bs[o * 49 + hh] = bf[i];
    }
    int base = blockIdx.x * NPB;                  // NN % 16 == 0
    for (int i = tid; i < NPB * HD; i += 256)
        hs[i] = ldf(h, (long long)base * HD + i, fb);
    {   // zero the vh pad dims 48..63 (16 nodes x 16 dims = 256 slots)
        int ln = tid >> 4, o = HD + (tid & 15);
        vh[(size_t)(base + ln) * VS + o] = (__half)0.f;
    }
    __syncthreads();
    for (int i = tid; i < NPB * HD; i += 256) {
        int ln = i / HD, o = i - ln * HD;
        const float* hr = hs + ln * HD;
        const float* wr = Ws + o * 49;
        const float* br = Bs + o * 49;
        float su = 0.f, sv = 0.f;
        #pragma unroll
        for (int k = 0; k < HD; ++k) { float hv = hr[k]; su += wr[k] * hv; sv += br[k] * hv; }
        int n = base + ln;
        uh[(size_t)n * HD + o] = __float2half(su);
        vh[(size_t)n * VS + o] = __float2half(sv);
    }
}

// ---------------------------------------------------------------------------
// binA (primary): SINGLE-PASS two-phase block-aggregated scatter into 1563
// coarse bins. Phase 1 decodes each thread's 4 triples (c,n1,n2,qw) into
// REGISTERS (compile-time-indexed arrays, rule #20) while building the LDS
// bin histogram -- idx/d1/d2 are read exactly once. Reserve: ONE global
// atomic per (block, non-empty bin) -> contiguous run. Phase 2 re-ranks via
// a second LDS counter and writes metas from registers.
// meta: x = n1 | qw15<<17 ; y = n2 | (c&63)<<17
// ---------------------------------------------------------------------------
__global__ __launch_bounds__(1024) void binA_kernel(
        const void* __restrict__ idxp,
        const void* __restrict__ d1p, const void* __restrict__ d2p,
        const int* __restrict__ flags, int* __restrict__ gcur,
        uint2* __restrict__ binned) {
    __shared__ int h1[NBIN];
    __shared__ int h2[NBIN];
    __shared__ int gb[NBIN];
    int tid = threadIdx.x;
    for (int i = tid; i < NBIN; i += 1024) { h1[i] = 0; h2[i] = 0; }
    __syncthreads();
    int t0 = blockIdx.x * CHK;
    int fb = flags[0], fi = flags[1];
    const int* qi = (const int*)idxp;             // int64: low words at even idx

    unsigned mx[TPT], my[TPT];
    int bn[TPT];
    #pragma unroll
    for (int j = 0; j < TPT; ++j) {               // phase 1: decode + histogram
        int t = t0 + j * 1024 + tid;
        if (t < NT) {
            int c, n1, n2;
            if (fi) {
                c  = qi[6LL * t];
                n1 = qi[6LL * t + 2];
                n2 = qi[6LL * t + 4];
            } else {
                c  = qi[3LL * t];
                n1 = qi[3LL * t + 1];
                n2 = qi[3LL * t + 2];
            }
            float d1 = ldf(d1p, t, fb);
            float d2 = ldf(d2p, t, fb);
            float asym = fabsf(d1 - d2) / (fmaxf(d1, d2) + 1e-8f);
            unsigned qw = (unsigned)((1.0f + 0.3f * asym) * WQUANT + 0.5f);
            if (qw > 32767u) qw = 32767u;
            bn[j] = c >> 6;
            mx[j] = (unsigned)n1 | (qw << 17);
            my[j] = (unsigned)n2 | ((unsigned)(c & 63) << 17);
            atomicAdd(&h1[bn[j]], 1);
        } else {
            bn[j] = -1;
        }
    }
    __syncthreads();
    for (int b = tid; b < NBIN; b += 1024) {      // reserve contiguous runs
        int n = h1[b];
        gb[b] = n ? atomicAdd(&gcur[b << 5], n) : 0;
    }
    __syncthreads();
    #pragma unroll
    for (int j = 0; j < TPT; ++j) {               // phase 2: rank + scatter
        if (bn[j] >= 0) {
            int r = atomicAdd(&h2[bn[j]], 1);
            int pos = gb[bn[j]] + r;
            if (pos < BINCAP)
                binned[(size_t)bn[j] * BINCAP + pos] = make_uint2(mx[j], my[j]);
        }
    }
}

// ---------------------------------------------------------------------------
// bin_accum (primary): one block per 64-center bin. Coalesced read of the
// bin's metas, LDS-atomic scatter into per-center LDS buckets (rows padded
// to 64 so the t+8+s probe stays in-row), then the proven per-wave accum
// (R2 form: 16 triples/trip, FOUR gathers issued back-to-back = 4 in
// flight; validity selects give w=0/row-0 for tail slots): lane=(s 0..7,
// dg 0..7), single-line uint4 gathers of 8 fp16 dims, packed-fp16
// leaky(p)*w = (.505w)p + (.495w)|p|, drained to f32 per 16 triples.
// Fused residual + LayerNorm epilogue. 8 waves x 8 centers each.
// LDS = 36.6 KB -> 4 blocks/CU (32 waves/CU).
// NOTE (R3 post-mortem): do NOT hand-pipeline this loop with named double
// buffers / conditional prefetch -- it serialized the gathers and added
// scratch traffic (79us -> 105us, WRITE +27MB). The straight-line 4-gather
// block IS the pipeline.
// ---------------------------------------------------------------------------
__global__ __launch_bounds__(512, 4) void bin_accum_kernel(
        const void* __restrict__ h, const int* __restrict__ flags,
        const __half* __restrict__ uh, const __half* __restrict__ vh,
        const int* __restrict__ gcur, const uint2* __restrict__ binned,
        const void* __restrict__ gamma, const void* __restrict__ beta,
        void* __restrict__ out) {
    __shared__ uint2 buckets[BINB][64];           // 32768 B, 56 slots used
    __shared__ int   cur[BINB];
    __shared__ float ucs[8][64];
    __shared__ float accs[8][HD];
    int tid = threadIdx.x, fb = flags[0];
    int bin = blockIdx.x;

    for (int i = tid; i < BINB; i += 512) cur[i] = 0;
    __syncthreads();

    int nm = gcur[bin << 5]; if (nm > BINCAP) nm = BINCAP;
    const uint2* bp = binned + (size_t)bin * BINCAP;
    for (int i = tid; i < nm; i += 512) {         // LDS bucket scatter
        uint2 m = bp[i];
        int cl = (m.y >> 17) & (BINB - 1);
        int r = atomicAdd(&cur[cl], 1);
        if (r < CAP) buckets[cl][r] = m;
    }
    __syncthreads();

    int wv = tid >> 6, lane = tid & 63;
    int s = lane >> 3, dg = lane & 7;
    const char* vb = (const char*)vh;
    size_t dgo = (size_t)dg * 16;
    float gv = (lane < HD) ? ldf(gamma, lane, fb) : 0.f;
    float bv = (lane < HD) ? ldf(beta, lane, fb) : 0.f;

    for (int ci = 0; ci < BINB / 8; ++ci) {       // 8 centers per wave
        int cl = wv * (BINB / 8) + ci;
        int n = bin * BINB + cl;
        if (n >= NN) continue;                    // last bin: tail centers

        int m = cur[cl]; if (m > CAP) m = CAP;
        float hval = (lane < HD) ? ldf(h, (long long)n * HD + lane, fb) : 0.f;
        float uval = (lane < HD) ? __half2float(uh[(size_t)n * HD + lane]) : 0.f;
        ucs[wv][lane] = uval;                     // wave-sync write->read
        hf2 uc4[4];
        #pragma unroll
        for (int j = 0; j < 4; ++j) {
            uc4[j].x = (_Float16)ucs[wv][dg * 8 + 2 * j];
            uc4[j].y = (_Float16)ucs[wv][dg * 8 + 2 * j + 1];
        }

        float accf[8] = {0.f, 0.f, 0.f, 0.f, 0.f, 0.f, 0.f, 0.f};
        for (int t = 0; t < m; t += 16) {
            uint2 m0 = buckets[cl][t + s];        // in padded row, LDS-safe
            uint2 m1 = buckets[cl][t + 8 + s];
            int v0 = (t + s) < m, v1 = (t + 8 + s) < m;
            unsigned a0 = v0 ? (m0.x & 0x1FFFFu) : 0u;
            unsigned b0 = v0 ? (m0.y & 0x1FFFFu) : 0u;
            float w0 = v0 ? (float)(m0.x >> 17) * WSCALE : 0.f;
            unsigned a1 = v1 ? (m1.x & 0x1FFFFu) : 0u;
            unsigned b1 = v1 ? (m1.y & 0x1FFFFu) : 0u;
            float w1 = v1 ? (float)(m1.x >> 17) * WSCALE : 0.f;
            V4H pa0, pb0, pa1, pb1;
            pa0.u = *(const uint4*)(vb + (size_t)a0 * 128 + dgo);
            pb0.u = *(const uint4*)(vb + (size_t)b0 * 128 + dgo);
            pa1.u = *(const uint4*)(vb + (size_t)a1 * 128 + dgo);
            pb1.u = *(const uint4*)(vb + (size_t)b1 * 128 + dgo);
            hf2 aw0 = splat2(0.505f * w0), bw0 = splat2(0.495f * w0);
            hf2 aw1 = splat2(0.505f * w1), bw1 = splat2(0.495f * w1);
            #pragma unroll
            for (int j = 0; j < 4; ++j) {
                hf2 p0 = pa0.h[j] + pb0.h[j] + uc4[j];
                hf2 acch = p0 * aw0 + habs2(p0) * bw0;
                hf2 p1 = pa1.h[j] + pb1.h[j] + uc4[j];
                acch += p1 * aw1 + habs2(p1) * bw1;
                accf[2 * j]     += (float)acch.x;
                accf[2 * j + 1] += (float)acch.y;
            }
        }

        // reduce across the 8 slot-copies (lane bits 3..5)
        #pragma unroll
        for (int j = 0; j < 8; ++j) {
            accf[j] += __shfl_xor(accf[j], 8, 64);
            accf[j] += __shfl_xor(accf[j], 16, 64);
            accf[j] += __shfl_xor(accf[j], 32, 64);
        }
        if (lane < 6) {                           // dims 0..47
            #pragma unroll
            for (int j = 0; j < 8; ++j) accs[wv][lane * 8 + j] = accf[j];
        }
        float av = (lane < HD) ? accs[wv][lane] : 0.f; // wave-sync

        float rnc = rsqrtf(fmaxf((float)m, 1.0f));
        float x = (lane < HD) ? (hval + av * rnc) : 0.f;
        float su = x, sq = x * x;
        #pragma unroll
        for (int o = 32; o; o >>= 1) {
            su += __shfl_xor(su, o, 64);
            sq += __shfl_xor(sq, o, 64);
        }
        float mu   = su * (1.0f / HD);
        float var  = sq * (1.0f / HD) - mu * mu;
        float rstd = rsqrtf(var + 1e-5f);
        if (lane < HD) {
            float r = (x - mu) * rstd * gv + bv;
            if (fb) ((__hip_bfloat16*)out)[(size_t)n * HD + lane] = __float2bfloat16(r);
            else    ((float*)out)[(size_t)n * HD + lane] = r;
        }
    }
}

// ---------------------------------------------------------------------------
// hist (fallback only): line-padded counters cnt[c<<4].
// ---------------------------------------------------------------------------
__global__ __launch_bounds__(256) void hist_kernel(const void* __restrict__ idxp,
                                                   const int* __restrict__ flags,
                                                   int* __restrict__ cnt) {
    int t = blockIdx.x * 256 + threadIdx.x;
    if (t >= NT) return;
    int c = flags[1] ? (int)((const long long*)idxp)[3LL * t]
                     : ((const int*)idxp)[3 * t];
    atomicAdd(&cnt[c << 4], 1);
}

// ---------------------------------------------------------------------------
// scans (fallback only): exclusive scan of cnt[i<<4] -> off[NN].
// ---------------------------------------------------------------------------
__global__ __launch_bounds__(1024) void scan_part(const int* __restrict__ cnt,
                                                  int* __restrict__ off,
                                                  int* __restrict__ bsum) {
    __shared__ int wsums[16];
    int tid = threadIdx.x, lane = tid & 63, wv = tid >> 6;
    int i = blockIdx.x * 1024 + tid;
    int x = (i < NN) ? cnt[i << 4] : 0;
    int vx = x;
    #pragma unroll
    for (int o = 1; o < 64; o <<= 1) {
        int y = __shfl_up(vx, o, 64);
        if (lane >= o) vx += y;
    }
    if (lane == 63) wsums[wv] = vx;
    __syncthreads();
    if (tid == 0) {
        int s = 0;
        #pragma unroll
        for (int k = 0; k < 16; ++k) { int t2 = wsums[k]; wsums[k] = s; s += t2; }
        bsum[blockIdx.x] = s;
    }
    __syncthreads();
    if (i < NN) off[i] = wsums[wv] + vx - x;
}

__global__ __launch_bounds__(1024) void scan_add(int* __restrict__ off,
                                                 const int* __restrict__ bsum) {
    int bid = blockIdx.x;
    int pre = 0;
    for (int k = 0; k < bid; ++k) pre += bsum[k];
    int i = bid * 1024 + threadIdx.x;
    if (i < NN) off[i] += pre;
}

// ---------------------------------------------------------------------------
// scatter (fallback only): meta = uint2{ n1 | qw<<17, n2 }.
// pos = atomicAdd(&off[c],1)  (off -> inclusive end)
// ---------------------------------------------------------------------------
__global__ __launch_bounds__(256) void scatter_kernel(
        const void* __restrict__ idxp,
        const void* __restrict__ d1p, const void* __restrict__ d2p,
        const int* __restrict__ flags, int* __restrict__ cur,
        uint2* __restrict__ sp) {
    int t = blockIdx.x * 256 + threadIdx.x;
    if (t >= NT) return;
    int fb = flags[0];
    int c, n1, n2;
    if (flags[1]) {
        const long long* q = (const long long*)idxp;
        c = (int)q[3LL * t]; n1 = (int)q[3LL * t + 1]; n2 = (int)q[3LL * t + 2];
    } else {
        const int* q = (const int*)idxp;
        c = q[3 * t]; n1 = q[3 * t + 1]; n2 = q[3 * t + 2];
    }
    float d1 = ldf(d1p, t, fb);
    float d2 = ldf(d2p, t, fb);
    float asym = fabsf(d1 - d2) / (fmaxf(d1, d2) + 1e-8f);
    unsigned int qw = (unsigned int)((1.0f + 0.3f * asym) * WQUANT + 0.5f);
    if (qw > 32767u) qw = 32767u;
    uint2 m = make_uint2((unsigned int)n1 | (qw << 17), (unsigned int)n2);
    int pos = atomicAdd(&cur[c], 1);
    sp[pos] = m;
}

// ---------------------------------------------------------------------------
// accum (fallback only): one wave per center, segment from off[].
// ---------------------------------------------------------------------------
__global__ __launch_bounds__(256) void accum_kernel(
        const void* __restrict__ h, const int* __restrict__ flags,
        const __half* __restrict__ uh, const __half* __restrict__ vh,
        const int* __restrict__ seg, const uint2* __restrict__ sp,
        const void* __restrict__ gamma, const void* __restrict__ beta,
        void* __restrict__ out) {
    __shared__ uint2 metas[4][64];
    __shared__ float ucs[4][64];
    __shared__ float accs[4][HD];
    int tid = threadIdx.x, fb = flags[0];
    int wv = tid >> 6, lane = tid & 63;
    int n = blockIdx.x * 4 + wv;                  // NN % 4 == 0

    float hval = (lane < HD) ? ldf(h, (long long)n * HD + lane, fb) : 0.f;
    float uval = (lane < HD) ? __half2float(uh[(size_t)n * HD + lane]) : 0.f;
    ucs[wv][lane] = uval;                         // wave-sync write->read

    int s = lane >> 3, dg = lane & 7;
    hf2 uc4[4];
    #pragma unroll
    for (int j = 0; j < 4; ++j) {
        uc4[j].x = (_Float16)ucs[wv][dg * 8 + 2 * j];
        uc4[j].y = (_Float16)ucs[wv][dg * 8 + 2 * j + 1];
    }

    int start = (n == 0) ? 0 : seg[n - 1];
    int end = seg[n];
    float accf[8] = {0.f, 0.f, 0.f, 0.f, 0.f, 0.f, 0.f, 0.f};
    const char* vb = (const char*)vh;
    size_t dgo = (size_t)dg * 16;

    for (int chunk = start; chunk < end; chunk += 64) {
        int m = end - chunk; if (m > 64) m = 64;
        if (lane < m) metas[wv][lane] = sp[chunk + lane];
        for (int t = 0; t < m; t += 16) {
            uint2 m0 = metas[wv][t + s];
            uint2 m1 = metas[wv][t + 8 + s];
            int v0 = (t + s) < m, v1 = (t + 8 + s) < m;
            unsigned a0 = v0 ? (m0.x & 0x1FFFFu) : 0u;
            unsigned b0 = v0 ? (m0.y & 0x1FFFFu) : 0u;
            float w0 = v0 ? (float)(m0.x >> 17) * WSCALE : 0.f;
            unsigned a1 = v1 ? (m1.x & 0x1FFFFu) : 0u;
            unsigned b1 = v1 ? (m1.y & 0x1FFFFu) : 0u;
            float w1 = v1 ? (float)(m1.x >> 17) * WSCALE : 0.f;
            V4H pa0, pb0, pa1, pb1;
            pa0.u = *(const uint4*)(vb + (size_t)a0 * 128 + dgo);
            pb0.u = *(const uint4*)(vb + (size_t)b0 * 128 + dgo);
            pa1.u = *(const uint4*)(vb + (size_t)a1 * 128 + dgo);
            pb1.u = *(const uint4*)(vb + (size_t)b1 * 128 + dgo);
            hf2 aw0 = splat2(0.505f * w0), bw0 = splat2(0.495f * w0);
            hf2 aw1 = splat2(0.505f * w1), bw1 = splat2(0.495f * w1);
            #pragma unroll
            for (int j = 0; j < 4; ++j) {
                hf2 p0 = pa0.h[j] + pb0.h[j] + uc4[j];
                hf2 acch = p0 * aw0 + habs2(p0) * bw0;
                hf2 p1 = pa1.h[j] + pb1.h[j] + uc4[j];
                acch += p1 * aw1 + habs2(p1) * bw1;
                accf[2 * j]     += (float)acch.x;
                accf[2 * j + 1] += (float)acch.y;
            }
        }
    }

    #pragma unroll
    for (int j = 0; j < 8; ++j) {
        accf[j] += __shfl_xor(accf[j], 8, 64);
        accf[j] += __shfl_xor(accf[j], 16, 64);
        accf[j] += __shfl_xor(accf[j], 32, 64);
    }
    if (lane < 6) {
        #pragma unroll
        for (int j = 0; j < 8; ++j) accs[wv][lane * 8 + j] = accf[j];
    }
    float av = (lane < HD) ? accs[wv][lane] : 0.f;

    float rnc = rsqrtf(fmaxf((float)(end - start), 1.0f));
    float x = (lane < HD) ? (hval + av * rnc) : 0.f;
    float su = x, sq = x * x;
    #pragma unroll
    for (int o = 32; o; o >>= 1) {
        su += __shfl_xor(su, o, 64);
        sq += __shfl_xor(sq, o, 64);
    }
    float mu   = su * (1.0f / HD);
    float var  = sq * (1.0f / HD) - mu * mu;
    float rstd = rsqrtf(var + 1e-5f);
    if (lane < HD) {
        float g  = ldf(gamma, lane, fb);
        float bb = ldf(beta, lane, fb);
        float r = (x - mu) * rstd * g + bb;
        if (fb) ((__hip_bfloat16*)out)[(size_t)n * HD + lane] = __float2bfloat16(r);
        else    ((float*)out)[(size_t)n * HD + lane] = r;
    }
}

extern "C" void kernel_launch(void* const* d_in, const int* in_sizes, int n_in,
                              void* d_out, int out_size, void* d_ws, size_t ws_size,
                              hipStream_t stream) {
    const void* h     = d_in[0];
    const void* idx   = d_in[1];
    const void* d1    = d_in[2];
    const void* d2    = d_in[3];
    const void* W3    = d_in[4];
    const void* Wu    = d_in[5];
    const void* gamma = d_in[6];
    const void* beta  = d_in[7];

    char* base  = (char*)d_ws;
    int*   flags = (int*)base;                              // 64 B
    float* wu1f  = (float*)(base + 64);                     // 2304 f
    float* bf    = wu1f + HD * HD;                          // 2304 f
    uintptr_t ua = (uintptr_t)(bf + HD * HD);
    __half* uh   = (__half*)((ua + 127) & ~(uintptr_t)127); // NN*48 fp16 (9.6 MB)
    __half* vh   = (__half*)((char*)uh + (size_t)NN * HD * 2); // NN*64 fp16 (12.8 MB)
    char*  after = (char*)vh + (size_t)NN * VS * 2;

    // Primary (coarse-bin) layout: gcur + binned after vh.
    int*   gcur = (int*)after;                              // NBIN*32 ints (200 KB)
    uintptr_t bna = (uintptr_t)(gcur + (size_t)NBIN * 32);
    uint2* binned = (uint2*)((bna + 127) & ~(uintptr_t)127); // NBIN*BINCAP*8 = 22.4 MB
    size_t need_primary = ((char*)(binned + (size_t)NBIN * BINCAP)) - base;

    // Fallback layout: cnt/off/bsum/sp after vh (R8 pipeline).
    int*   cnt  = (int*)after;                              // NN*16 ints (6.4 MB)
    int*   off  = (int*)(cnt + (size_t)NN * 16);            // NN
    int*   bsum = off + NN;                                 // NB (+pad)
    uintptr_t spa = (uintptr_t)(bsum + 256);
    uint2* sp   = (uint2*)((spa + 15) & ~(uintptr_t)15);    // NT uint2 (16 MB)

    prep_kernel<<<(HD * HD + 255) / 256, 256, 0, stream>>>(
        (const unsigned int*)h, (const unsigned int*)idx, flags, W3, Wu, wu1f, bf);
    node_kernel<<<NN / NPB, 256, 0, stream>>>(h, flags, wu1f, bf, uh, vh);

    if (ws_size >= need_primary) {
        // ---- coarse-bin path: aggregated bin scatter + fused bucket/accum ----
        hipMemsetAsync(gcur, 0, (size_t)NBIN * 32 * sizeof(int), stream);
        binA_kernel<<<NCHK, 1024, 0, stream>>>(idx, d1, d2, flags, gcur, binned);
        bin_accum_kernel<<<NBIN, 512, 0, stream>>>(h, flags, uh, vh, gcur, binned,
                                                   gamma, beta, d_out);
    } else {
        // ---- fallback: hist + scan + sorted scatter (R8 pipeline) ----
        hipMemsetAsync(cnt, 0, (size_t)NN * 16 * sizeof(int), stream);
        hist_kernel<<<NBH, 256, 0, stream>>>(idx, flags, cnt);
        scan_part<<<NB, 1024, 0, stream>>>(cnt, off, bsum);
        scan_add<<<NB, 1024, 0, stream>>>(off, bsum);
        scatter_kernel<<<(NT + 255) / 256, 256, 0, stream>>>(
            idx, d1, d2, flags, off, sp);
        accum_kernel<<<NN / 4, 256, 0, stream>>>(h, flags, uh, vh, off, sp,
                                                 gamma, beta, d_out);
    }
}

// Round 6
// 265.140 us; speedup vs baseline: 1.1774x; 1.0391x over previous
//
#include <hip/hip_runtime.h>
#include <hip/hip_bf16.h>
#include <hip/hip_fp16.h>
#include <stdint.h>

#define NN 100000
#define NT 2000000
#define HD 48
#define VS 64                     // vh row stride in halfs (128 B, line-aligned)
#define CAP 56                    // per-center bucket capacity; P(Poisson(20) >= 56) ~ 4e-10
#define NPB 16                    // nodes per node_kernel block
#define NBH ((NT + 255) / 256)
#define NB ((NN + 1023) / 1024)   // 98 scan blocks (fallback)

// ---- coarse-bin pipeline (primary path) ----
#define BINB 64                       // centers per coarse bin
#define NBIN ((NN + BINB - 1) / BINB) // 1563
#define BINCAP 1792                   // metas/bin cap: mean 1280, sigma 35.8 -> +14.3σ
#define CHK 8192                      // triples per binA block (run length ~5.2 -> less write amp)
#define NCHK ((NT + CHK - 1) / CHK)   // 245
#define TPT (CHK / 1024)              // 8 triples per binA thread (reg-held)

// weight encoding: w = qw * (1.3/32767); real triples give qw in [25206,32767].
#define WSCALE (1.3f / 32767.0f)
#define WQUANT (32767.0f / 1.3f)

typedef _Float16 hf2 __attribute__((ext_vector_type(2)));

__device__ __forceinline__ float b2f(__hip_bfloat16 x) { return __bfloat162float(x); }

// Load a "float tensor" element whose storage is bf16 (flag=1) or f32 (flag=0).
__device__ __forceinline__ float ldf(const void* p, long long i, int isbf16) {
    if (isbf16) return b2f(((const __hip_bfloat16*)p)[i]);
    return ((const float*)p)[i];
}

__device__ __forceinline__ hf2 habs2(hf2 x) {
    union { hf2 h; unsigned int u; } c; c.h = x; c.u &= 0x7FFF7FFFu; return c.h;
}
__device__ __forceinline__ hf2 splat2(float f) {
    hf2 r; r.x = (_Float16)f; r.y = (_Float16)f; return r;
}
union V4H { uint4 u; hf2 h[4]; };

// ---------------------------------------------------------------------------
// prep (9 blocks): self-probe dtypes, fold weights.
// wu1f[o][k] = Wu[o][k];  bf[o][k] = sum_j Wu[o][48+j] * W3[j][k]
// ---------------------------------------------------------------------------
__global__ __launch_bounds__(256) void prep_kernel(
        const unsigned int* __restrict__ hw, const unsigned int* __restrict__ iw,
        int* __restrict__ flags,
        const void* __restrict__ W3, const void* __restrict__ Wu,
        float* __restrict__ wu1f, float* __restrict__ bf) {
    __shared__ int cbf, cix;
    int tid = threadIdx.x;
    if (tid == 0) { cbf = 0; cix = 0; }
    __syncthreads();
    unsigned int e = (hw[tid] >> 7) & 0xff;       // exponent of low-half bf16
    if (e >= 90 && e <= 144) atomicAdd(&cbf, 1);
    if (blockIdx.x == 0 && iw[2 * tid + 1] == 0) atomicAdd(&cix, 1);
    __syncthreads();
    int fb = (cbf >= 192) ? 1 : 0;                // bf16 ~256 hits; f32 ~55
    if (blockIdx.x == 0 && tid == 0) {
        flags[0] = fb;
        flags[1] = (cix >= 255) ? 1 : 0;          // int64 high words all zero
    }
    int i = blockIdx.x * 256 + tid;
    if (i < HD * HD) {
        int o = i / HD, hh = i % HD;
        wu1f[i] = ldf(Wu, o * 2 * HD + hh, fb);
        float s = 0.f;
        #pragma unroll 8
        for (int k = 0; k < HD; ++k)
            s += ldf(Wu, o * 2 * HD + HD + k, fb) * ldf(W3, k * HD + hh, fb);
        bf[i] = s;
    }
}

// ---------------------------------------------------------------------------
// node: u[n]=Wu1*h[n] (fp16 stride-48), v[n]=M*h[n] (fp16 stride-64 = 128 B
// line-aligned rows, dims 48..63 zeroed so gathers are single-line and the
// dg=6,7 lanes read zeros). 16 nodes/block amortizes the 18.4 KB W broadcast.
// ---------------------------------------------------------------------------
__global__ __launch_bounds__(256) void node_kernel(
        const void* __restrict__ h, const int* __restrict__ flags,
        const float* __restrict__ wu1f, const float* __restrict__ bf,
        __half* __restrict__ uh, __half* __restrict__ vh) {
    __shared__ float Ws[HD * 49];
    __shared__ float Bs[HD * 49];
    __shared__ float hs[NPB * HD];
    int tid = threadIdx.x;
    int fb = flags[0];
    for (int i = tid; i < HD * HD; i += 256) {
        int o = i / HD, hh = i % HD;
        Ws[o * 49 + hh] = wu1f[i];
        Bs[o * 49 + hh] = bf[i];
    }
    int base = blockIdx.x * NPB;                  // NN % 16 == 0
    for (int i = tid; i < NPB * HD; i += 256)
        hs[i] = ldf(h, (long long)base * HD + i, fb);
    {   // zero the vh pad dims 48..63 (16 nodes x 16 dims = 256 slots)
        int ln = tid >> 4, o = HD + (tid & 15);
        vh[(size_t)(base + ln) * VS + o] = (__half)0.f;
    }
    __syncthreads();
    for (int i = tid; i < NPB * HD; i += 256) {
        int ln = i / HD, o = i - ln * HD;
        const float* hr = hs + ln * HD;
        const float* wr = Ws + o * 49;
        const float* br = Bs + o * 49;
        float su = 0.f, sv = 0.f;
        #pragma unroll
        for (int k = 0; k < HD; ++k) { float hv = hr[k]; su += wr[k] * hv; sv += br[k] * hv; }
        int n = base + ln;
        uh[(size_t)n * HD + o] = __float2half(su);
        vh[(size_t)n * VS + o] = __float2half(sv);
    }
}

// ---------------------------------------------------------------------------
// binA (primary): SINGLE-PASS two-phase block-aggregated scatter into 1563
// coarse bins. Phase 1 decodes each thread's 8 triples (c,n1,n2,qw) into
// REGISTERS (compile-time-indexed arrays, rule #20) while building the LDS
// bin histogram -- idx/d1/d2 are read exactly once. Reserve: ONE global
// atomic per (block, non-empty bin) -> contiguous run (avg 5.2 entries ->
// ~half the partial-line writeback of CHK=4096). Phase 2 re-ranks via a
// second LDS counter and writes metas from registers.
// meta: x = n1 | qw15<<17 ; y = n2 | (c&63)<<17
// ---------------------------------------------------------------------------
__global__ __launch_bounds__(1024, 4) void binA_kernel(
        const void* __restrict__ idxp,
        const void* __restrict__ d1p, const void* __restrict__ d2p,
        const int* __restrict__ flags, int* __restrict__ gcur,
        uint2* __restrict__ binned) {
    __shared__ int h1[NBIN];
    __shared__ int h2[NBIN];
    __shared__ int gb[NBIN];
    int tid = threadIdx.x;
    for (int i = tid; i < NBIN; i += 1024) { h1[i] = 0; h2[i] = 0; }
    __syncthreads();
    int t0 = blockIdx.x * CHK;
    int fb = flags[0], fi = flags[1];
    const int* qi = (const int*)idxp;             // int64: low words at even idx

    unsigned mx[TPT], my[TPT];
    int bn[TPT];
    #pragma unroll
    for (int j = 0; j < TPT; ++j) {               // phase 1: decode + histogram
        int t = t0 + j * 1024 + tid;
        if (t < NT) {
            int c, n1, n2;
            if (fi) {
                c  = qi[6LL * t];
                n1 = qi[6LL * t + 2];
                n2 = qi[6LL * t + 4];
            } else {
                c  = qi[3LL * t];
                n1 = qi[3LL * t + 1];
                n2 = qi[3LL * t + 2];
            }
            float d1 = ldf(d1p, t, fb);
            float d2 = ldf(d2p, t, fb);
            float asym = fabsf(d1 - d2) / (fmaxf(d1, d2) + 1e-8f);
            unsigned qw = (unsigned)((1.0f + 0.3f * asym) * WQUANT + 0.5f);
            if (qw > 32767u) qw = 32767u;
            bn[j] = c >> 6;
            mx[j] = (unsigned)n1 | (qw << 17);
            my[j] = (unsigned)n2 | ((unsigned)(c & 63) << 17);
            atomicAdd(&h1[bn[j]], 1);
        } else {
            bn[j] = -1;
        }
    }
    __syncthreads();
    for (int b = tid; b < NBIN; b += 1024) {      // reserve contiguous runs
        int n = h1[b];
        gb[b] = n ? atomicAdd(&gcur[b << 5], n) : 0;
    }
    __syncthreads();
    #pragma unroll
    for (int j = 0; j < TPT; ++j) {               // phase 2: rank + scatter
        if (bn[j] >= 0) {
            int r = atomicAdd(&h2[bn[j]], 1);
            int pos = gb[bn[j]] + r;
            if (pos < BINCAP)
                binned[(size_t)bn[j] * BINCAP + pos] = make_uint2(mx[j], my[j]);
        }
    }
}

// ---------------------------------------------------------------------------
// bin_accum (primary): one block per 64-center bin. Coalesced read of the
// bin's metas, LDS-atomic scatter into per-center LDS buckets (rows padded
// to 64 so all probes stay in-row), then the per-wave accum with a WIDENED
// straight-line trip: 32 triples/trip, EIGHT gathers issued back-to-back
// (8 lines in flight per wave; 97% of centers finish in ONE latency round
// since P(m>32)~0.5%). Validity selects give w=0/row-0 for tail slots.
// lane=(s 0..7, dg 0..7), single-line uint4 gathers of 8 fp16 dims,
// packed-fp16 leaky(p)*w = (.505w)p + (.495w)|p|, drained to f32 per trip.
// Fused residual + LayerNorm epilogue. 8 waves x 8 centers each.
// LDS = 36.6 KB; launch_bounds(512,6) caps VGPR at 85 (expect ~70).
// NOTE (R3 post-mortem): do NOT hand-pipeline this loop with named double
// buffers / conditional prefetch -- it serialized the gathers and added
// scratch traffic (79us -> 105us, WRITE +27MB). Straight-line widening is
// the only safe way to raise MLP here.
// ---------------------------------------------------------------------------
__global__ __launch_bounds__(512, 6) void bin_accum_kernel(
        const void* __restrict__ h, const int* __restrict__ flags,
        const __half* __restrict__ uh, const __half* __restrict__ vh,
        const int* __restrict__ gcur, const uint2* __restrict__ binned,
        const void* __restrict__ gamma, const void* __restrict__ beta,
        void* __restrict__ out) {
    __shared__ uint2 buckets[BINB][64];           // 32768 B, 56 slots used
    __shared__ int   cur[BINB];
    __shared__ float ucs[8][64];
    __shared__ float accs[8][HD];
    int tid = threadIdx.x, fb = flags[0];
    int bin = blockIdx.x;

    for (int i = tid; i < BINB; i += 512) cur[i] = 0;
    __syncthreads();

    int nm = gcur[bin << 5]; if (nm > BINCAP) nm = BINCAP;
    const uint2* bp = binned + (size_t)bin * BINCAP;
    for (int i = tid; i < nm; i += 512) {         // LDS bucket scatter
        uint2 m = bp[i];
        int cl = (m.y >> 17) & (BINB - 1);
        int r = atomicAdd(&cur[cl], 1);
        if (r < CAP) buckets[cl][r] = m;
    }
    __syncthreads();

    int wv = tid >> 6, lane = tid & 63;
    int s = lane >> 3, dg = lane & 7;
    const char* vb = (const char*)vh;
    size_t dgo = (size_t)dg * 16;
    float gv = (lane < HD) ? ldf(gamma, lane, fb) : 0.f;
    float bv = (lane < HD) ? ldf(beta, lane, fb) : 0.f;

    for (int ci = 0; ci < BINB / 8; ++ci) {       // 8 centers per wave
        int cl = wv * (BINB / 8) + ci;
        int n = bin * BINB + cl;
        if (n >= NN) continue;                    // last bin: tail centers

        int m = cur[cl]; if (m > CAP) m = CAP;
        float hval = (lane < HD) ? ldf(h, (long long)n * HD + lane, fb) : 0.f;
        float uval = (lane < HD) ? __half2float(uh[(size_t)n * HD + lane]) : 0.f;
        ucs[wv][lane] = uval;                     // wave-sync write->read
        hf2 uc4[4];
        #pragma unroll
        for (int j = 0; j < 4; ++j) {
            uc4[j].x = (_Float16)ucs[wv][dg * 8 + 2 * j];
            uc4[j].y = (_Float16)ucs[wv][dg * 8 + 2 * j + 1];
        }

        float accf[8] = {0.f, 0.f, 0.f, 0.f, 0.f, 0.f, 0.f, 0.f};
        for (int t = 0; t < m; t += 32) {
            // metas for 4 slot-groups (max probe index 32+24+7=63, in-row)
            uint2 m0 = buckets[cl][t + s];
            uint2 m1 = buckets[cl][t + 8 + s];
            uint2 m2 = buckets[cl][t + 16 + s];
            uint2 m3 = buckets[cl][t + 24 + s];
            int v0 = (t + s) < m,      v1 = (t + 8 + s) < m;
            int v2 = (t + 16 + s) < m, v3 = (t + 24 + s) < m;
            unsigned a0 = v0 ? (m0.x & 0x1FFFFu) : 0u;
            unsigned b0 = v0 ? (m0.y & 0x1FFFFu) : 0u;
            float w0 = v0 ? (float)(m0.x >> 17) * WSCALE : 0.f;
            unsigned a1 = v1 ? (m1.x & 0x1FFFFu) : 0u;
            unsigned b1 = v1 ? (m1.y & 0x1FFFFu) : 0u;
            float w1 = v1 ? (float)(m1.x >> 17) * WSCALE : 0.f;
            unsigned a2 = v2 ? (m2.x & 0x1FFFFu) : 0u;
            unsigned b2 = v2 ? (m2.y & 0x1FFFFu) : 0u;
            float w2 = v2 ? (float)(m2.x >> 17) * WSCALE : 0.f;
            unsigned a3 = v3 ? (m3.x & 0x1FFFFu) : 0u;
            unsigned b3 = v3 ? (m3.y & 0x1FFFFu) : 0u;
            float w3 = v3 ? (float)(m3.x >> 17) * WSCALE : 0.f;
            // 8 gathers issued back-to-back: 8 lines in flight
            V4H pa0, pb0, pa1, pb1, pa2, pb2, pa3, pb3;
            pa0.u = *(const uint4*)(vb + (size_t)a0 * 128 + dgo);
            pb0.u = *(const uint4*)(vb + (size_t)b0 * 128 + dgo);
            pa1.u = *(const uint4*)(vb + (size_t)a1 * 128 + dgo);
            pb1.u = *(const uint4*)(vb + (size_t)b1 * 128 + dgo);
            pa2.u = *(const uint4*)(vb + (size_t)a2 * 128 + dgo);
            pb2.u = *(const uint4*)(vb + (size_t)b2 * 128 + dgo);
            pa3.u = *(const uint4*)(vb + (size_t)a3 * 128 + dgo);
            pb3.u = *(const uint4*)(vb + (size_t)b3 * 128 + dgo);
            hf2 aw0 = splat2(0.505f * w0), bw0 = splat2(0.495f * w0);
            hf2 aw1 = splat2(0.505f * w1), bw1 = splat2(0.495f * w1);
            hf2 aw2 = splat2(0.505f * w2), bw2 = splat2(0.495f * w2);
            hf2 aw3 = splat2(0.505f * w3), bw3 = splat2(0.495f * w3);
            #pragma unroll
            for (int j = 0; j < 4; ++j) {
                hf2 p0 = pa0.h[j] + pb0.h[j] + uc4[j];
                hf2 acch = p0 * aw0 + habs2(p0) * bw0;
                hf2 p1 = pa1.h[j] + pb1.h[j] + uc4[j];
                acch += p1 * aw1 + habs2(p1) * bw1;
                hf2 p2 = pa2.h[j] + pb2.h[j] + uc4[j];
                acch += p2 * aw2 + habs2(p2) * bw2;
                hf2 p3 = pa3.h[j] + pb3.h[j] + uc4[j];
                acch += p3 * aw3 + habs2(p3) * bw3;
                accf[2 * j]     += (float)acch.x;
                accf[2 * j + 1] += (float)acch.y;
            }
        }

        // reduce across the 8 slot-copies (lane bits 3..5)
        #pragma unroll
        for (int j = 0; j < 8; ++j) {
            accf[j] += __shfl_xor(accf[j], 8, 64);
            accf[j] += __shfl_xor(accf[j], 16, 64);
            accf[j] += __shfl_xor(accf[j], 32, 64);
        }
        if (lane < 6) {                           // dims 0..47
            #pragma unroll
            for (int j = 0; j < 8; ++j) accs[wv][lane * 8 + j] = accf[j];
        }
        float av = (lane < HD) ? accs[wv][lane] : 0.f; // wave-sync

        float rnc = rsqrtf(fmaxf((float)m, 1.0f));
        float x = (lane < HD) ? (hval + av * rnc) : 0.f;
        float su = x, sq = x * x;
        #pragma unroll
        for (int o = 32; o; o >>= 1) {
            su += __shfl_xor(su, o, 64);
            sq += __shfl_xor(sq, o, 64);
        }
        float mu   = su * (1.0f / HD);
        float var  = sq * (1.0f / HD) - mu * mu;
        float rstd = rsqrtf(var + 1e-5f);
        if (lane < HD) {
            float r = (x - mu) * rstd * gv + bv;
            if (fb) ((__hip_bfloat16*)out)[(size_t)n * HD + lane] = __float2bfloat16(r);
            else    ((float*)out)[(size_t)n * HD + lane] = r;
        }
    }
}

// ---------------------------------------------------------------------------
// hist (fallback only): line-padded counters cnt[c<<4].
// ---------------------------------------------------------------------------
__global__ __launch_bounds__(256) void hist_kernel(const void* __restrict__ idxp,
                                                   const int* __restrict__ flags,
                                                   int* __restrict__ cnt) {
    int t = blockIdx.x * 256 + threadIdx.x;
    if (t >= NT) return;
    int c = flags[1] ? (int)((const long long*)idxp)[3LL * t]
                     : ((const int*)idxp)[3 * t];
    atomicAdd(&cnt[c << 4], 1);
}

// ---------------------------------------------------------------------------
// scans (fallback only): exclusive scan of cnt[i<<4] -> off[NN].
// ---------------------------------------------------------------------------
__global__ __launch_bounds__(1024) void scan_part(const int* __restrict__ cnt,
                                                  int* __restrict__ off,
                                                  int* __restrict__ bsum) {
    __shared__ int wsums[16];
    int tid = threadIdx.x, lane = tid & 63, wv = tid >> 6;
    int i = blockIdx.x * 1024 + tid;
    int x = (i < NN) ? cnt[i << 4] : 0;
    int vx = x;
    #pragma unroll
    for (int o = 1; o < 64; o <<= 1) {
        int y = __shfl_up(vx, o, 64);
        if (lane >= o) vx += y;
    }
    if (lane == 63) wsums[wv] = vx;
    __syncthreads();
    if (tid == 0) {
        int s = 0;
        #pragma unroll
        for (int k = 0; k < 16; ++k) { int t2 = wsums[k]; wsums[k] = s; s += t2; }
        bsum[blockIdx.x] = s;
    }
    __syncthreads();
    if (i < NN) off[i] = wsums[wv] + vx - x;
}

__global__ __launch_bounds__(1024) void scan_add(int* __restrict__ off,
                                                 const int* __restrict__ bsum) {
    int bid = blockIdx.x;
    int pre = 0;
    for (int k = 0; k < bid; ++k) pre += bsum[k];
    int i = bid * 1024 + threadIdx.x;
    if (i < NN) off[i] += pre;
}

// ---------------------------------------------------------------------------
// scatter (fallback only): meta = uint2{ n1 | qw<<17, n2 }.
// pos = atomicAdd(&off[c],1)  (off -> inclusive end)
// ---------------------------------------------------------------------------
__global__ __launch_bounds__(256) void scatter_kernel(
        const void* __restrict__ idxp,
        const void* __restrict__ d1p, const void* __restrict__ d2p,
        const int* __restrict__ flags, int* __restrict__ cur,
        uint2* __restrict__ sp) {
    int t = blockIdx.x * 256 + threadIdx.x;
    if (t >= NT) return;
    int fb = flags[0];
    int c, n1, n2;
    if (flags[1]) {
        const long long* q = (const long long*)idxp;
        c = (int)q[3LL * t]; n1 = (int)q[3LL * t + 1]; n2 = (int)q[3LL * t + 2];
    } else {
        const int* q = (const int*)idxp;
        c = q[3 * t]; n1 = q[3 * t + 1]; n2 = q[3 * t + 2];
    }
    float d1 = ldf(d1p, t, fb);
    float d2 = ldf(d2p, t, fb);
    float asym = fabsf(d1 - d2) / (fmaxf(d1, d2) + 1e-8f);
    unsigned int qw = (unsigned int)((1.0f + 0.3f * asym) * WQUANT + 0.5f);
    if (qw > 32767u) qw = 32767u;
    uint2 m = make_uint2((unsigned int)n1 | (qw << 17), (unsigned int)n2);
    int pos = atomicAdd(&cur[c], 1);
    sp[pos] = m;
}

// ---------------------------------------------------------------------------
// accum (fallback only): one wave per center, segment from off[].
// ---------------------------------------------------------------------------
__global__ __launch_bounds__(256) void accum_kernel(
        const void* __restrict__ h, const int* __restrict__ flags,
        const __half* __restrict__ uh, const __half* __restrict__ vh,
        const int* __restrict__ seg, const uint2* __restrict__ sp,
        const void* __restrict__ gamma, const void* __restrict__ beta,
        void* __restrict__ out) {
    __shared__ uint2 metas[4][64];
    __shared__ float ucs[4][64];
    __shared__ float accs[4][HD];
    int tid = threadIdx.x, fb = flags[0];
    int wv = tid >> 6, lane = tid & 63;
    int n = blockIdx.x * 4 + wv;                  // NN % 4 == 0

    float hval = (lane < HD) ? ldf(h, (long long)n * HD + lane, fb) : 0.f;
    float uval = (lane < HD) ? __half2float(uh[(size_t)n * HD + lane]) : 0.f;
    ucs[wv][lane] = uval;                         // wave-sync write->read

    int s = lane >> 3, dg = lane & 7;
    hf2 uc4[4];
    #pragma unroll
    for (int j = 0; j < 4; ++j) {
        uc4[j].x = (_Float16)ucs[wv][dg * 8 + 2 * j];
        uc4[j].y = (_Float16)ucs[wv][dg * 8 + 2 * j + 1];
    }

    int start = (n == 0) ? 0 : seg[n - 1];
    int end = seg[n];
    float accf[8] = {0.f, 0.f, 0.f, 0.f, 0.f, 0.f, 0.f, 0.f};
    const char* vb = (const char*)vh;
    size_t dgo = (size_t)dg * 16;

    for (int chunk = start; chunk < end; chunk += 64) {
        int m = end - chunk; if (m > 64) m = 64;
        if (lane < m) metas[wv][lane] = sp[chunk + lane];
        for (int t = 0; t < m; t += 16) {
            uint2 m0 = metas[wv][t + s];
            uint2 m1 = metas[wv][t + 8 + s];
            int v0 = (t + s) < m, v1 = (t + 8 + s) < m;
            unsigned a0 = v0 ? (m0.x & 0x1FFFFu) : 0u;
            unsigned b0 = v0 ? (m0.y & 0x1FFFFu) : 0u;
            float w0 = v0 ? (float)(m0.x >> 17) * WSCALE : 0.f;
            unsigned a1 = v1 ? (m1.x & 0x1FFFFu) : 0u;
            unsigned b1 = v1 ? (m1.y & 0x1FFFFu) : 0u;
            float w1 = v1 ? (float)(m1.x >> 17) * WSCALE : 0.f;
            V4H pa0, pb0, pa1, pb1;
            pa0.u = *(const uint4*)(vb + (size_t)a0 * 128 + dgo);
            pb0.u = *(const uint4*)(vb + (size_t)b0 * 128 + dgo);
            pa1.u = *(const uint4*)(vb + (size_t)a1 * 128 + dgo);
            pb1.u = *(const uint4*)(vb + (size_t)b1 * 128 + dgo);
            hf2 aw0 = splat2(0.505f * w0), bw0 = splat2(0.495f * w0);
            hf2 aw1 = splat2(0.505f * w1), bw1 = splat2(0.495f * w1);
            #pragma unroll
            for (int j = 0; j < 4; ++j) {
                hf2 p0 = pa0.h[j] + pb0.h[j] + uc4[j];
                hf2 acch = p0 * aw0 + habs2(p0) * bw0;
                hf2 p1 = pa1.h[j] + pb1.h[j] + uc4[j];
                acch += p1 * aw1 + habs2(p1) * bw1;
                accf[2 * j]     += (float)acch.x;
                accf[2 * j + 1] += (float)acch.y;
            }
        }
    }

    #pragma unroll
    for (int j = 0; j < 8; ++j) {
        accf[j] += __shfl_xor(accf[j], 8, 64);
        accf[j] += __shfl_xor(accf[j], 16, 64);
        accf[j] += __shfl_xor(accf[j], 32, 64);
    }
    if (lane < 6) {
        #pragma unroll
        for (int j = 0; j < 8; ++j) accs[wv][lane * 8 + j] = accf[j];
    }
    float av = (lane < HD) ? accs[wv][lane] : 0.f;

    float rnc = rsqrtf(fmaxf((float)(end - start), 1.0f));
    float x = (lane < HD) ? (hval + av * rnc) : 0.f;
    float su = x, sq = x * x;
    #pragma unroll
    for (int o = 32; o; o >>= 1) {
        su += __shfl_xor(su, o, 64);
        sq += __shfl_xor(sq, o, 64);
    }
    float mu   = su * (1.0f / HD);
    float var  = sq * (1.0f / HD) - mu * mu;
    float rstd = rsqrtf(var + 1e-5f);
    if (lane < HD) {
        float g  = ldf(gamma, lane, fb);
        float bb = ldf(beta, lane, fb);
        float r = (x - mu) * rstd * g + bb;
        if (fb) ((__hip_bfloat16*)out)[(size_t)n * HD + lane] = __float2bfloat16(r);
        else    ((float*)out)[(size_t)n * HD + lane] = r;
    }
}

extern "C" void kernel_launch(void* const* d_in, const int* in_sizes, int n_in,
                              void* d_out, int out_size, void* d_ws, size_t ws_size,
                              hipStream_t stream) {
    const void* h     = d_in[0];
    const void* idx   = d_in[1];
    const void* d1    = d_in[2];
    const void* d2    = d_in[3];
    const void* W3    = d_in[4];
    const void* Wu    = d_in[5];
    const void* gamma = d_in[6];
    const void* beta  = d_in[7];

    char* base  = (char*)d_ws;
    int*   flags = (int*)base;                              // 64 B
    float* wu1f  = (float*)(base + 64);                     // 2304 f
    float* bf    = wu1f + HD * HD;                          // 2304 f
    uintptr_t ua = (uintptr_t)(bf + HD * HD);
    __half* uh   = (__half*)((ua + 127) & ~(uintptr_t)127); // NN*48 fp16 (9.6 MB)
    __half* vh   = (__half*)((char*)uh + (size_t)NN * HD * 2); // NN*64 fp16 (12.8 MB)
    char*  after = (char*)vh + (size_t)NN * VS * 2;

    // Primary (coarse-bin) layout: gcur + binned after vh.
    int*   gcur = (int*)after;                              // NBIN*32 ints (200 KB)
    uintptr_t bna = (uintptr_t)(gcur + (size_t)NBIN * 32);
    uint2* binned = (uint2*)((bna + 127) & ~(uintptr_t)127); // NBIN*BINCAP*8 = 22.4 MB
    size_t need_primary = ((char*)(binned + (size_t)NBIN * BINCAP)) - base;

    // Fallback layout: cnt/off/bsum/sp after vh (R8 pipeline).
    int*   cnt  = (int*)after;                              // NN*16 ints (6.4 MB)
    int*   off  = (int*)(cnt + (size_t)NN * 16);            // NN
    int*   bsum = off + NN;                                 // NB (+pad)
    uintptr_t spa = (uintptr_t)(bsum + 256);
    uint2* sp   = (uint2*)((spa + 15) & ~(uintptr_t)15);    // NT uint2 (16 MB)

    prep_kernel<<<(HD * HD + 255) / 256, 256, 0, stream>>>(
        (const unsigned int*)h, (const unsigned int*)idx, flags, W3, Wu, wu1f, bf);
    node_kernel<<<NN / NPB, 256, 0, stream>>>(h, flags, wu1f, bf, uh, vh);

    if (ws_size >= need_primary) {
        // ---- coarse-bin path: aggregated bin scatter + fused bucket/accum ----
        hipMemsetAsync(gcur, 0, (size_t)NBIN * 32 * sizeof(int), stream);
        binA_kernel<<<NCHK, 1024, 0, stream>>>(idx, d1, d2, flags, gcur, binned);
        bin_accum_kernel<<<NBIN, 512, 0, stream>>>(h, flags, uh, vh, gcur, binned,
                                                   gamma, beta, d_out);
    } else {
        // ---- fallback: hist + scan + sorted scatter (R8 pipeline) ----
        hipMemsetAsync(cnt, 0, (size_t)NN * 16 * sizeof(int), stream);
        hist_kernel<<<NBH, 256, 0, stream>>>(idx, flags, cnt);
        scan_part<<<NB, 1024, 0, stream>>>(cnt, off, bsum);
        scan_add<<<NB, 1024, 0, stream>>>(off, bsum);
        scatter_kernel<<<(NT + 255) / 256, 256, 0, stream>>>(
            idx, d1, d2, flags, off, sp);
        accum_kernel<<<NN / 4, 256, 0, stream>>>(h, flags, uh, vh, off, sp,
                                                 gamma, beta, d_out);
    }
}

// Round 7
// 261.065 us; speedup vs baseline: 1.1958x; 1.0156x over previous
//
#include <hip/hip_runtime.h>
#include <hip/hip_bf16.h>
#include <hip/hip_fp16.h>
#include <stdint.h>

#define NN 100000
#define NT 2000000
#define HD 48
#define VS 64                     // vh row stride in halfs (128 B, line-aligned)
#define CAP 56                    // per-center bucket capacity; P(Poisson(20) >= 56) ~ 4e-10
#define NPB 20                    // nodes per fused-node block (NN % 20 == 0)
#define NBH ((NT + 255) / 256)
#define NB ((NN + 1023) / 1024)   // 98 scan blocks (fallback)

// ---- coarse-bin pipeline (primary path) ----
#define BINB 64                       // centers per coarse bin
#define NBIN ((NN + BINB - 1) / BINB) // 1563
#define BINCAP 1792                   // metas/bin cap: mean 1280, sigma 35.8 -> +14.3σ
#define CHK 8192                      // triples per binA block (run length ~5.2)
#define NCHK ((NT + CHK - 1) / CHK)   // 245
#define TPT (CHK / 1024)              // 8 triples per binA thread (reg-held)
#define NNODEB (NN / NPB)             // 5000 node tiles
#define FATGRID (NCHK + NNODEB)       // binA blocks first (long), node blocks fill

// weight encoding: w = qw * (1.3/32767); real triples give qw in [25206,32767].
#define WSCALE (1.3f / 32767.0f)
#define WQUANT (32767.0f / 1.3f)

typedef _Float16 hf2 __attribute__((ext_vector_type(2)));

__device__ __forceinline__ float b2f(__hip_bfloat16 x) { return __bfloat162float(x); }

// Load a "float tensor" element whose storage is bf16 (flag=1) or f32 (flag=0).
__device__ __forceinline__ float ldf(const void* p, long long i, int isbf16) {
    if (isbf16) return b2f(((const __hip_bfloat16*)p)[i]);
    return ((const float*)p)[i];
}

__device__ __forceinline__ hf2 habs2(hf2 x) {
    union { hf2 h; unsigned int u; } c; c.h = x; c.u &= 0x7FFF7FFFu; return c.h;
}
__device__ __forceinline__ hf2 splat2(float f) {
    hf2 r; r.x = (_Float16)f; r.y = (_Float16)f; return r;
}
union V4H { uint4 u; hf2 h[4]; };

// ---------------------------------------------------------------------------
// prep (9 blocks): self-probe dtypes, fold weights, zero gcur (absorbs the
// old 200 KB memset dispatch).
// wu1f[o][k] = Wu[o][k];  bf[o][k] = sum_j Wu[o][48+j] * W3[j][k]
// ---------------------------------------------------------------------------
__global__ __launch_bounds__(256) void prep_kernel(
        const unsigned int* __restrict__ hw, const unsigned int* __restrict__ iw,
        int* __restrict__ flags,
        const void* __restrict__ W3, const void* __restrict__ Wu,
        float* __restrict__ wu1f, float* __restrict__ bf,
        int* __restrict__ gcur) {
    __shared__ int cbf, cix;
    int tid = threadIdx.x;
    if (tid == 0) { cbf = 0; cix = 0; }
    __syncthreads();
    unsigned int e = (hw[tid] >> 7) & 0xff;       // exponent of low-half bf16
    if (e >= 90 && e <= 144) atomicAdd(&cbf, 1);
    if (blockIdx.x == 0 && iw[2 * tid + 1] == 0) atomicAdd(&cix, 1);
    __syncthreads();
    int fb = (cbf >= 192) ? 1 : 0;                // bf16 ~256 hits; f32 ~55
    if (blockIdx.x == 0 && tid == 0) {
        flags[0] = fb;
        flags[1] = (cix >= 255) ? 1 : 0;          // int64 high words all zero
    }
    for (int i = blockIdx.x * 256 + tid; i < NBIN * 32; i += 9 * 256)
        gcur[i] = 0;
    int i = blockIdx.x * 256 + tid;
    if (i < HD * HD) {
        int o = i / HD, hh = i % HD;
        wu1f[i] = ldf(Wu, o * 2 * HD + hh, fb);
        float s = 0.f;
        #pragma unroll 8
        for (int k = 0; k < HD; ++k)
            s += ldf(Wu, o * 2 * HD + HD + k, fb) * ldf(W3, k * HD + hh, fb);
        bf[i] = s;
    }
}

// ---------------------------------------------------------------------------
// fused_nb (primary): node-transform and binA are DATA-INDEPENDENT, so one
// fat kernel runs both concurrently. Blocks 0..NCHK-1 = binA chunks (long,
// launched first so they start immediately); blocks NCHK.. = 20-node tiles
// filling the remaining CU capacity. 1024 threads, LDS = union of the two
// parts (22.7 KB).
//
// binA part: SINGLE-PASS two-phase block-aggregated scatter into 1563
// coarse bins. Phase 1 decodes 8 triples/thread (c,n1,n2,qw) into REGISTERS
// (compile-time-indexed, rule #20) while building the LDS bin histogram --
// idx/d1/d2 read exactly once. Reserve: ONE global atomic per (block,
// non-empty bin) -> contiguous run (~5.2 entries). Phase 2 re-ranks via a
// second LDS counter, writes metas from registers.
// meta: x = n1 | qw15<<17 ; y = n2 | (c&63)<<17
//
// node part: u[n]=Wu1*h[n] (fp16 stride-48), v[n]=M*h[n] (fp16 stride-64 =
// 128 B line-aligned rows, dims 48..63 zeroed so gathers are single-line).
// ---------------------------------------------------------------------------
struct NodeLds { float Ws[HD * 49]; float Bs[HD * 49]; float hs[NPB * HD]; };
struct BinLds  { int h1[NBIN]; int h2[NBIN]; int gb[NBIN]; };
union FatLds   { NodeLds n; BinLds b; };

__global__ __launch_bounds__(1024, 2) void fused_nb_kernel(
        const void* __restrict__ h, const int* __restrict__ flags,
        const float* __restrict__ wu1f, const float* __restrict__ bf,
        __half* __restrict__ uh, __half* __restrict__ vh,
        const void* __restrict__ idxp,
        const void* __restrict__ d1p, const void* __restrict__ d2p,
        int* __restrict__ gcur, uint2* __restrict__ binned) {
    __shared__ FatLds L;
    int tid = threadIdx.x;
    int fb = flags[0];

    if (blockIdx.x < NCHK) {
        // ---------------- binA part ----------------
        int fi = flags[1];
        for (int i = tid; i < NBIN; i += 1024) { L.b.h1[i] = 0; L.b.h2[i] = 0; }
        __syncthreads();
        int t0 = blockIdx.x * CHK;
        const int* qi = (const int*)idxp;         // int64: low words at even idx

        unsigned mx[TPT], my[TPT];
        int bn[TPT];
        #pragma unroll
        for (int j = 0; j < TPT; ++j) {           // phase 1: decode + histogram
            int t = t0 + j * 1024 + tid;
            if (t < NT) {
                int c, n1, n2;
                if (fi) {
                    c  = qi[6LL * t];
                    n1 = qi[6LL * t + 2];
                    n2 = qi[6LL * t + 4];
                } else {
                    c  = qi[3LL * t];
                    n1 = qi[3LL * t + 1];
                    n2 = qi[3LL * t + 2];
                }
                float d1 = ldf(d1p, t, fb);
                float d2 = ldf(d2p, t, fb);
                float asym = fabsf(d1 - d2) / (fmaxf(d1, d2) + 1e-8f);
                unsigned qw = (unsigned)((1.0f + 0.3f * asym) * WQUANT + 0.5f);
                if (qw > 32767u) qw = 32767u;
                bn[j] = c >> 6;
                mx[j] = (unsigned)n1 | (qw << 17);
                my[j] = (unsigned)n2 | ((unsigned)(c & 63) << 17);
                atomicAdd(&L.b.h1[bn[j]], 1);
            } else {
                bn[j] = -1;
            }
        }
        __syncthreads();
        for (int b = tid; b < NBIN; b += 1024) {  // reserve contiguous runs
            int n = L.b.h1[b];
            L.b.gb[b] = n ? atomicAdd(&gcur[b << 5], n) : 0;
        }
        __syncthreads();
        #pragma unroll
        for (int j = 0; j < TPT; ++j) {           // phase 2: rank + scatter
            if (bn[j] >= 0) {
                int r = atomicAdd(&L.b.h2[bn[j]], 1);
                int pos = L.b.gb[bn[j]] + r;
                if (pos < BINCAP)
                    binned[(size_t)bn[j] * BINCAP + pos] = make_uint2(mx[j], my[j]);
            }
        }
    } else {
        // ---------------- node part ----------------
        int base = (blockIdx.x - NCHK) * NPB;     // NN % 20 == 0
        for (int i = tid; i < HD * HD; i += 1024) {
            int o = i / HD, hh = i % HD;
            L.n.Ws[o * 49 + hh] = wu1f[i];
            L.n.Bs[o * 49 + hh] = bf[i];
        }
        for (int i = tid; i < NPB * HD; i += 1024)
            L.n.hs[i] = ldf(h, (long long)base * HD + i, fb);
        if (tid < NPB * 16) {  // zero the vh pad dims 48..63
            int ln = tid >> 4, o = HD + (tid & 15);
            vh[(size_t)(base + ln) * VS + o] = (__half)0.f;
        }
        __syncthreads();
        for (int i = tid; i < NPB * HD; i += 1024) {
            int ln = i / HD, o = i - ln * HD;
            const float* hr = L.n.hs + ln * HD;
            const float* wr = L.n.Ws + o * 49;
            const float* br = L.n.Bs + o * 49;
            float su = 0.f, sv = 0.f;
            #pragma unroll
            for (int k = 0; k < HD; ++k) { float hv = hr[k]; su += wr[k] * hv; sv += br[k] * hv; }
            int n = base + ln;
            uh[(size_t)n * HD + o] = __float2half(su);
            vh[(size_t)n * VS + o] = __float2half(sv);
        }
    }
}

// ---------------------------------------------------------------------------
// bin_accum (primary): one block per 64-center bin. Coalesced read of the
// bin's metas, LDS-atomic scatter into per-center LDS buckets (rows padded
// to 64 so the t+8+s probe stays in-row), then the proven per-wave accum
// (R5 form: 16 triples/trip, FOUR gathers issued back-to-back; validity
// selects give w=0/row-0 for tail slots): lane=(s 0..7, dg 0..7),
// single-line uint4 gathers of 8 fp16 dims, packed-fp16
// leaky(p)*w = (.505w)p + (.495w)|p|, drained to f32 per 16 triples.
// Fused residual + LayerNorm epilogue. 8 waves x 8 centers each.
// LDS = 36.6 KB -> 4 blocks/CU (32 waves/CU).
// NOTE (R3/R6 post-mortems): do NOT hand-pipeline (R3: 79->105us) and do
// NOT widen to 32-trip/8-gather (R6: 78.6->81.5us, VGPR 40, Occ -11pts).
// The 16-trip straight-line 4-gather block is a verified local optimum.
// ---------------------------------------------------------------------------
__global__ __launch_bounds__(512, 4) void bin_accum_kernel(
        const void* __restrict__ h, const int* __restrict__ flags,
        const __half* __restrict__ uh, const __half* __restrict__ vh,
        const int* __restrict__ gcur, const uint2* __restrict__ binned,
        const void* __restrict__ gamma, const void* __restrict__ beta,
        void* __restrict__ out) {
    __shared__ uint2 buckets[BINB][64];           // 32768 B, 56 slots used
    __shared__ int   cur[BINB];
    __shared__ float ucs[8][64];
    __shared__ float accs[8][HD];
    int tid = threadIdx.x, fb = flags[0];
    int bin = blockIdx.x;

    for (int i = tid; i < BINB; i += 512) cur[i] = 0;
    __syncthreads();

    int nm = gcur[bin << 5]; if (nm > BINCAP) nm = BINCAP;
    const uint2* bp = binned + (size_t)bin * BINCAP;
    for (int i = tid; i < nm; i += 512) {         // LDS bucket scatter
        uint2 m = bp[i];
        int cl = (m.y >> 17) & (BINB - 1);
        int r = atomicAdd(&cur[cl], 1);
        if (r < CAP) buckets[cl][r] = m;
    }
    __syncthreads();

    int wv = tid >> 6, lane = tid & 63;
    int s = lane >> 3, dg = lane & 7;
    const char* vb = (const char*)vh;
    size_t dgo = (size_t)dg * 16;
    float gv = (lane < HD) ? ldf(gamma, lane, fb) : 0.f;
    float bv = (lane < HD) ? ldf(beta, lane, fb) : 0.f;

    for (int ci = 0; ci < BINB / 8; ++ci) {       // 8 centers per wave
        int cl = wv * (BINB / 8) + ci;
        int n = bin * BINB + cl;
        if (n >= NN) continue;                    // last bin: tail centers

        int m = cur[cl]; if (m > CAP) m = CAP;
        float hval = (lane < HD) ? ldf(h, (long long)n * HD + lane, fb) : 0.f;
        float uval = (lane < HD) ? __half2float(uh[(size_t)n * HD + lane]) : 0.f;
        ucs[wv][lane] = uval;                     // wave-sync write->read
        hf2 uc4[4];
        #pragma unroll
        for (int j = 0; j < 4; ++j) {
            uc4[j].x = (_Float16)ucs[wv][dg * 8 + 2 * j];
            uc4[j].y = (_Float16)ucs[wv][dg * 8 + 2 * j + 1];
        }

        float accf[8] = {0.f, 0.f, 0.f, 0.f, 0.f, 0.f, 0.f, 0.f};
        for (int t = 0; t < m; t += 16) {
            uint2 m0 = buckets[cl][t + s];        // in padded row, LDS-safe
            uint2 m1 = buckets[cl][t + 8 + s];
            int v0 = (t + s) < m, v1 = (t + 8 + s) < m;
            unsigned a0 = v0 ? (m0.x & 0x1FFFFu) : 0u;
            unsigned b0 = v0 ? (m0.y & 0x1FFFFu) : 0u;
            float w0 = v0 ? (float)(m0.x >> 17) * WSCALE : 0.f;
            unsigned a1 = v1 ? (m1.x & 0x1FFFFu) : 0u;
            unsigned b1 = v1 ? (m1.y & 0x1FFFFu) : 0u;
            float w1 = v1 ? (float)(m1.x >> 17) * WSCALE : 0.f;
            V4H pa0, pb0, pa1, pb1;
            pa0.u = *(const uint4*)(vb + (size_t)a0 * 128 + dgo);
            pb0.u = *(const uint4*)(vb + (size_t)b0 * 128 + dgo);
            pa1.u = *(const uint4*)(vb + (size_t)a1 * 128 + dgo);
            pb1.u = *(const uint4*)(vb + (size_t)b1 * 128 + dgo);
            hf2 aw0 = splat2(0.505f * w0), bw0 = splat2(0.495f * w0);
            hf2 aw1 = splat2(0.505f * w1), bw1 = splat2(0.495f * w1);
            #pragma unroll
            for (int j = 0; j < 4; ++j) {
                hf2 p0 = pa0.h[j] + pb0.h[j] + uc4[j];
                hf2 acch = p0 * aw0 + habs2(p0) * bw0;
                hf2 p1 = pa1.h[j] + pb1.h[j] + uc4[j];
                acch += p1 * aw1 + habs2(p1) * bw1;
                accf[2 * j]     += (float)acch.x;
                accf[2 * j + 1] += (float)acch.y;
            }
        }

        // reduce across the 8 slot-copies (lane bits 3..5)
        #pragma unroll
        for (int j = 0; j < 8; ++j) {
            accf[j] += __shfl_xor(accf[j], 8, 64);
            accf[j] += __shfl_xor(accf[j], 16, 64);
            accf[j] += __shfl_xor(accf[j], 32, 64);
        }
        if (lane < 6) {                           // dims 0..47
            #pragma unroll
            for (int j = 0; j < 8; ++j) accs[wv][lane * 8 + j] = accf[j];
        }
        float av = (lane < HD) ? accs[wv][lane] : 0.f; // wave-sync

        float rnc = rsqrtf(fmaxf((float)m, 1.0f));
        float x = (lane < HD) ? (hval + av * rnc) : 0.f;
        float su = x, sq = x * x;
        #pragma unroll
        for (int o = 32; o; o >>= 1) {
            su += __shfl_xor(su, o, 64);
            sq += __shfl_xor(sq, o, 64);
        }
        float mu   = su * (1.0f / HD);
        float var  = sq * (1.0f / HD) - mu * mu;
        float rstd = rsqrtf(var + 1e-5f);
        if (lane < HD) {
            float r = (x - mu) * rstd * gv + bv;
            if (fb) ((__hip_bfloat16*)out)[(size_t)n * HD + lane] = __float2bfloat16(r);
            else    ((float*)out)[(size_t)n * HD + lane] = r;
        }
    }
}

// ---------------------------------------------------------------------------
// node (fallback only): u[n]=Wu1*h[n], v[n]=M*h[n].
// ---------------------------------------------------------------------------
__global__ __launch_bounds__(256) void node_kernel(
        const void* __restrict__ h, const int* __restrict__ flags,
        const float* __restrict__ wu1f, const float* __restrict__ bf,
        __half* __restrict__ uh, __half* __restrict__ vh) {
    __shared__ float Ws[HD * 49];
    __shared__ float Bs[HD * 49];
    __shared__ float hs[16 * HD];
    int tid = threadIdx.x;
    int fb = flags[0];
    for (int i = tid; i < HD * HD; i += 256) {
        int o = i / HD, hh = i % HD;
        Ws[o * 49 + hh] = wu1f[i];
        Bs[o * 49 + hh] = bf[i];
    }
    int base = blockIdx.x * 16;                   // NN % 16 == 0
    for (int i = tid; i < 16 * HD; i += 256)
        hs[i] = ldf(h, (long long)base * HD + i, fb);
    {   // zero the vh pad dims 48..63
        int ln = tid >> 4, o = HD + (tid & 15);
        vh[(size_t)(base + ln) * VS + o] = (__half)0.f;
    }
    __syncthreads();
    for (int i = tid; i < 16 * HD; i += 256) {
        int ln = i / HD, o = i - ln * HD;
        const float* hr = hs + ln * HD;
        const float* wr = Ws + o * 49;
        const float* br = Bs + o * 49;
        float su = 0.f, sv = 0.f;
        #pragma unroll
        for (int k = 0; k < HD; ++k) { float hv = hr[k]; su += wr[k] * hv; sv += br[k] * hv; }
        int n = base + ln;
        uh[(size_t)n * HD + o] = __float2half(su);
        vh[(size_t)n * VS + o] = __float2half(sv);
    }
}

// ---------------------------------------------------------------------------
// hist (fallback only): line-padded counters cnt[c<<4].
// ---------------------------------------------------------------------------
__global__ __launch_bounds__(256) void hist_kernel(const void* __restrict__ idxp,
                                                   const int* __restrict__ flags,
                                                   int* __restrict__ cnt) {
    int t = blockIdx.x * 256 + threadIdx.x;
    if (t >= NT) return;
    int c = flags[1] ? (int)((const long long*)idxp)[3LL * t]
                     : ((const int*)idxp)[3 * t];
    atomicAdd(&cnt[c << 4], 1);
}

// ---------------------------------------------------------------------------
// scans (fallback only): exclusive scan of cnt[i<<4] -> off[NN].
// ---------------------------------------------------------------------------
__global__ __launch_bounds__(1024) void scan_part(const int* __restrict__ cnt,
                                                  int* __restrict__ off,
                                                  int* __restrict__ bsum) {
    __shared__ int wsums[16];
    int tid = threadIdx.x, lane = tid & 63, wv = tid >> 6;
    int i = blockIdx.x * 1024 + tid;
    int x = (i < NN) ? cnt[i << 4] : 0;
    int vx = x;
    #pragma unroll
    for (int o = 1; o < 64; o <<= 1) {
        int y = __shfl_up(vx, o, 64);
        if (lane >= o) vx += y;
    }
    if (lane == 63) wsums[wv] = vx;
    __syncthreads();
    if (tid == 0) {
        int s = 0;
        #pragma unroll
        for (int k = 0; k < 16; ++k) { int t2 = wsums[k]; wsums[k] = s; s += t2; }
        bsum[blockIdx.x] = s;
    }
    __syncthreads();
    if (i < NN) off[i] = wsums[wv] + vx - x;
}

__global__ __launch_bounds__(1024) void scan_add(int* __restrict__ off,
                                                 const int* __restrict__ bsum) {
    int bid = blockIdx.x;
    int pre = 0;
    for (int k = 0; k < bid; ++k) pre += bsum[k];
    int i = bid * 1024 + threadIdx.x;
    if (i < NN) off[i] += pre;
}

// ---------------------------------------------------------------------------
// scatter (fallback only): meta = uint2{ n1 | qw<<17, n2 }.
// pos = atomicAdd(&off[c],1)  (off -> inclusive end)
// ---------------------------------------------------------------------------
__global__ __launch_bounds__(256) void scatter_kernel(
        const void* __restrict__ idxp,
        const void* __restrict__ d1p, const void* __restrict__ d2p,
        const int* __restrict__ flags, int* __restrict__ cur,
        uint2* __restrict__ sp) {
    int t = blockIdx.x * 256 + threadIdx.x;
    if (t >= NT) return;
    int fb = flags[0];
    int c, n1, n2;
    if (flags[1]) {
        const long long* q = (const long long*)idxp;
        c = (int)q[3LL * t]; n1 = (int)q[3LL * t + 1]; n2 = (int)q[3LL * t + 2];
    } else {
        const int* q = (const int*)idxp;
        c = q[3 * t]; n1 = q[3 * t + 1]; n2 = q[3 * t + 2];
    }
    float d1 = ldf(d1p, t, fb);
    float d2 = ldf(d2p, t, fb);
    float asym = fabsf(d1 - d2) / (fmaxf(d1, d2) + 1e-8f);
    unsigned int qw = (unsigned int)((1.0f + 0.3f * asym) * WQUANT + 0.5f);
    if (qw > 32767u) qw = 32767u;
    uint2 m = make_uint2((unsigned int)n1 | (qw << 17), (unsigned int)n2);
    int pos = atomicAdd(&cur[c], 1);
    sp[pos] = m;
}

// ---------------------------------------------------------------------------
// accum (fallback only): one wave per center, segment from off[].
// ---------------------------------------------------------------------------
__global__ __launch_bounds__(256) void accum_kernel(
        const void* __restrict__ h, const int* __restrict__ flags,
        const __half* __restrict__ uh, const __half* __restrict__ vh,
        const int* __restrict__ seg, const uint2* __restrict__ sp,
        const void* __restrict__ gamma, const void* __restrict__ beta,
        void* __restrict__ out) {
    __shared__ uint2 metas[4][64];
    __shared__ float ucs[4][64];
    __shared__ float accs[4][HD];
    int tid = threadIdx.x, fb = flags[0];
    int wv = tid >> 6, lane = tid & 63;
    int n = blockIdx.x * 4 + wv;                  // NN % 4 == 0

    float hval = (lane < HD) ? ldf(h, (long long)n * HD + lane, fb) : 0.f;
    float uval = (lane < HD) ? __half2float(uh[(size_t)n * HD + lane]) : 0.f;
    ucs[wv][lane] = uval;                         // wave-sync write->read

    int s = lane >> 3, dg = lane & 7;
    hf2 uc4[4];
    #pragma unroll
    for (int j = 0; j < 4; ++j) {
        uc4[j].x = (_Float16)ucs[wv][dg * 8 + 2 * j];
        uc4[j].y = (_Float16)ucs[wv][dg * 8 + 2 * j + 1];
    }

    int start = (n == 0) ? 0 : seg[n - 1];
    int end = seg[n];
    float accf[8] = {0.f, 0.f, 0.f, 0.f, 0.f, 0.f, 0.f, 0.f};
    const char* vb = (const char*)vh;
    size_t dgo = (size_t)dg * 16;

    for (int chunk = start; chunk < end; chunk += 64) {
        int m = end - chunk; if (m > 64) m = 64;
        if (lane < m) metas[wv][lane] = sp[chunk + lane];
        for (int t = 0; t < m; t += 16) {
            uint2 m0 = metas[wv][t + s];
            uint2 m1 = metas[wv][t + 8 + s];
            int v0 = (t + s) < m, v1 = (t + 8 + s) < m;
            unsigned a0 = v0 ? (m0.x & 0x1FFFFu) : 0u;
            unsigned b0 = v0 ? (m0.y & 0x1FFFFu) : 0u;
            float w0 = v0 ? (float)(m0.x >> 17) * WSCALE : 0.f;
            unsigned a1 = v1 ? (m1.x & 0x1FFFFu) : 0u;
            unsigned b1 = v1 ? (m1.y & 0x1FFFFu) : 0u;
            float w1 = v1 ? (float)(m1.x >> 17) * WSCALE : 0.f;
            V4H pa0, pb0, pa1, pb1;
            pa0.u = *(const uint4*)(vb + (size_t)a0 * 128 + dgo);
            pb0.u = *(const uint4*)(vb + (size_t)b0 * 128 + dgo);
            pa1.u = *(const uint4*)(vb + (size_t)a1 * 128 + dgo);
            pb1.u = *(const uint4*)(vb + (size_t)b1 * 128 + dgo);
            hf2 aw0 = splat2(0.505f * w0), bw0 = splat2(0.495f * w0);
            hf2 aw1 = splat2(0.505f * w1), bw1 = splat2(0.495f * w1);
            #pragma unroll
            for (int j = 0; j < 4; ++j) {
                hf2 p0 = pa0.h[j] + pb0.h[j] + uc4[j];
                hf2 acch = p0 * aw0 + habs2(p0) * bw0;
                hf2 p1 = pa1.h[j] + pb1.h[j] + uc4[j];
                acch += p1 * aw1 + habs2(p1) * bw1;
                accf[2 * j]     += (float)acch.x;
                accf[2 * j + 1] += (float)acch.y;
            }
        }
    }

    #pragma unroll
    for (int j = 0; j < 8; ++j) {
        accf[j] += __shfl_xor(accf[j], 8, 64);
        accf[j] += __shfl_xor(accf[j], 16, 64);
        accf[j] += __shfl_xor(accf[j], 32, 64);
    }
    if (lane < 6) {
        #pragma unroll
        for (int j = 0; j < 8; ++j) accs[wv][lane * 8 + j] = accf[j];
    }
    float av = (lane < HD) ? accs[wv][lane] : 0.f;

    float rnc = rsqrtf(fmaxf((float)(end - start), 1.0f));
    float x = (lane < HD) ? (hval + av * rnc) : 0.f;
    float su = x, sq = x * x;
    #pragma unroll
    for (int o = 32; o; o >>= 1) {
        su += __shfl_xor(su, o, 64);
        sq += __shfl_xor(sq, o, 64);
    }
    float mu   = su * (1.0f / HD);
    float var  = sq * (1.0f / HD) - mu * mu;
    float rstd = rsqrtf(var + 1e-5f);
    if (lane < HD) {
        float g  = ldf(gamma, lane, fb);
        float bb = ldf(beta, lane, fb);
        float r = (x - mu) * rstd * g + bb;
        if (fb) ((__hip_bfloat16*)out)[(size_t)n * HD + lane] = __float2bfloat16(r);
        else    ((float*)out)[(size_t)n * HD + lane] = r;
    }
}

extern "C" void kernel_launch(void* const* d_in, const int* in_sizes, int n_in,
                              void* d_out, int out_size, void* d_ws, size_t ws_size,
                              hipStream_t stream) {
    const void* h     = d_in[0];
    const void* idx   = d_in[1];
    const void* d1    = d_in[2];
    const void* d2    = d_in[3];
    const void* W3    = d_in[4];
    const void* Wu    = d_in[5];
    const void* gamma = d_in[6];
    const void* beta  = d_in[7];

    char* base  = (char*)d_ws;
    int*   flags = (int*)base;                              // 64 B
    float* wu1f  = (float*)(base + 64);                     // 2304 f
    float* bf    = wu1f + HD * HD;                          // 2304 f
    uintptr_t ua = (uintptr_t)(bf + HD * HD);
    __half* uh   = (__half*)((ua + 127) & ~(uintptr_t)127); // NN*48 fp16 (9.6 MB)
    __half* vh   = (__half*)((char*)uh + (size_t)NN * HD * 2); // NN*64 fp16 (12.8 MB)
    char*  after = (char*)vh + (size_t)NN * VS * 2;

    // Primary (coarse-bin) layout: gcur + binned after vh.
    int*   gcur = (int*)after;                              // NBIN*32 ints (200 KB)
    uintptr_t bna = (uintptr_t)(gcur + (size_t)NBIN * 32);
    uint2* binned = (uint2*)((bna + 127) & ~(uintptr_t)127); // NBIN*BINCAP*8 = 22.4 MB
    size_t need_primary = ((char*)(binned + (size_t)NBIN * BINCAP)) - base;

    // Fallback layout: cnt/off/bsum/sp after vh (R8 pipeline).
    int*   cnt  = (int*)after;                              // NN*16 ints (6.4 MB)
    int*   off  = (int*)(cnt + (size_t)NN * 16);            // NN
    int*   bsum = off + NN;                                 // NB (+pad)
    uintptr_t spa = (uintptr_t)(bsum + 256);
    uint2* sp   = (uint2*)((spa + 15) & ~(uintptr_t)15);    // NT uint2 (16 MB)

    prep_kernel<<<(HD * HD + 255) / 256, 256, 0, stream>>>(
        (const unsigned int*)h, (const unsigned int*)idx, flags, W3, Wu,
        wu1f, bf, gcur);

    if (ws_size >= need_primary) {
        // ---- coarse-bin path: fused (node || binA) + bucket/accum ----
        fused_nb_kernel<<<FATGRID, 1024, 0, stream>>>(
            h, flags, wu1f, bf, uh, vh, idx, d1, d2, gcur, binned);
        bin_accum_kernel<<<NBIN, 512, 0, stream>>>(h, flags, uh, vh, gcur, binned,
                                                   gamma, beta, d_out);
    } else {
        // ---- fallback: hist + scan + sorted scatter (R8 pipeline) ----
        node_kernel<<<NN / 16, 256, 0, stream>>>(h, flags, wu1f, bf, uh, vh);
        hipMemsetAsync(cnt, 0, (size_t)NN * 16 * sizeof(int), stream);
        hist_kernel<<<NBH, 256, 0, stream>>>(idx, flags, cnt);
        scan_part<<<NB, 1024, 0, stream>>>(cnt, off, bsum);
        scan_add<<<NB, 1024, 0, stream>>>(off, bsum);
        scatter_kernel<<<(NT + 255) / 256, 256, 0, stream>>>(
            idx, d1, d2, flags, off, sp);
        accum_kernel<<<NN / 4, 256, 0, stream>>>(h, flags, uh, vh, off, sp,
                                                 gamma, beta, d_out);
    }
}

// Round 8
// 259.871 us; speedup vs baseline: 1.2012x; 1.0046x over previous
//
#include <hip/hip_runtime.h>
#include <hip/hip_bf16.h>
#include <hip/hip_fp16.h>
#include <stdint.h>

#define NN 100000
#define NT 2000000
#define HD 48
#define VS 64                     // vh row stride in halfs (128 B, line-aligned)
#define CAP 56                    // per-center bucket capacity; P(Poisson(20) >= 56) ~ 4e-10
#define NPB 20                    // nodes per fused-node block (NN % 20 == 0)
#define NBH ((NT + 255) / 256)
#define NB ((NN + 1023) / 1024)   // 98 scan blocks (fallback)

// ---- coarse-bin pipeline (primary path) ----
#define BINB 64                       // centers per coarse bin
#define NBIN ((NN + BINB - 1) / BINB) // 1563
#define BINCAP 1792                   // metas/bin cap: mean 1280, sigma 35.8 -> +14.3σ
#define CHK 8192                      // triples per binA block (run length ~5.2)
#define NCHK ((NT + CHK - 1) / CHK)   // 245
#define NNODEB (NN / NPB)             // 5000 node tiles
#define FATGRID (NCHK + NNODEB)       // binA blocks first (long), node blocks fill

// weight encoding: w = qw * (1.3/32767); real triples give qw in [25206,32767].
#define WSCALE (1.3f / 32767.0f)
#define WQUANT (32767.0f / 1.3f)

typedef _Float16 hf2 __attribute__((ext_vector_type(2)));

__device__ __forceinline__ float b2f(__hip_bfloat16 x) { return __bfloat162float(x); }

// Load a "float tensor" element whose storage is bf16 (flag=1) or f32 (flag=0).
__device__ __forceinline__ float ldf(const void* p, long long i, int isbf16) {
    if (isbf16) return b2f(((const __hip_bfloat16*)p)[i]);
    return ((const float*)p)[i];
}

__device__ __forceinline__ hf2 habs2(hf2 x) {
    union { hf2 h; unsigned int u; } c; c.h = x; c.u &= 0x7FFF7FFFu; return c.h;
}
__device__ __forceinline__ hf2 splat2(float f) {
    hf2 r; r.x = (_Float16)f; r.y = (_Float16)f; return r;
}
union V4H { uint4 u; hf2 h[4]; };

// ---------------------------------------------------------------------------
// prep (9 blocks): self-probe dtypes, fold weights, zero gcur.
// wu1f[o][k] = Wu[o][k];  bf[o][k] = sum_j Wu[o][48+j] * W3[j][k]
// ---------------------------------------------------------------------------
__global__ __launch_bounds__(256) void prep_kernel(
        const unsigned int* __restrict__ hw, const unsigned int* __restrict__ iw,
        int* __restrict__ flags,
        const void* __restrict__ W3, const void* __restrict__ Wu,
        float* __restrict__ wu1f, float* __restrict__ bf,
        int* __restrict__ gcur) {
    __shared__ int cbf, cix;
    int tid = threadIdx.x;
    if (tid == 0) { cbf = 0; cix = 0; }
    __syncthreads();
    unsigned int e = (hw[tid] >> 7) & 0xff;       // exponent of low-half bf16
    if (e >= 90 && e <= 144) atomicAdd(&cbf, 1);
    if (blockIdx.x == 0 && iw[2 * tid + 1] == 0) atomicAdd(&cix, 1);
    __syncthreads();
    int fb = (cbf >= 192) ? 1 : 0;                // bf16 ~256 hits; f32 ~55
    if (blockIdx.x == 0 && tid == 0) {
        flags[0] = fb;
        flags[1] = (cix >= 255) ? 1 : 0;          // int64 high words all zero
    }
    for (int i = blockIdx.x * 256 + tid; i < NBIN * 32; i += 9 * 256)
        gcur[i] = 0;
    int i = blockIdx.x * 256 + tid;
    if (i < HD * HD) {
        int o = i / HD, hh = i % HD;
        wu1f[i] = ldf(Wu, o * 2 * HD + hh, fb);
        float s = 0.f;
        #pragma unroll 8
        for (int k = 0; k < HD; ++k)
            s += ldf(Wu, o * 2 * HD + HD + k, fb) * ldf(W3, k * HD + hh, fb);
        bf[i] = s;
    }
}

// ---------------------------------------------------------------------------
// fused_nb (primary): node-transform and binA are DATA-INDEPENDENT; one fat
// kernel runs both. Blocks 0..NCHK-1 = binA chunks (long, start first);
// blocks NCHK.. = 20-node tiles filling remaining CU capacity.
//
// binA part (R7 post-mortem fix): the 24 reg-held meta values were array-
// indexed and the compiler DEMOTED THEM TO SCRATCH (VGPR_Count=20 < live
// data; WRITE_SIZE +25-35MB variable = spill traffic). Now: 32 NAMED
// SCALARS via macro unrolling + rank captured in phase 1
// (rk = atomicAdd(&h1[bn],1) during decode), h2 re-rank pass DELETED
// (halves LDS atomics). Phase 2 is pure writes at gb[bn]+rk.
// meta: x = n1 | qw15<<17 ; y = n2 | (c&63)<<17
//
// node part: u[n]=Wu1*h[n] (fp16 stride-48), v[n]=M*h[n] (fp16 stride-64 =
// 128 B line-aligned rows, dims 48..63 zeroed so gathers are single-line).
// ---------------------------------------------------------------------------
struct NodeLds { float Ws[HD * 49]; float Bs[HD * 49]; float hs[NPB * HD]; };
struct BinLds  { int h1[NBIN]; int gb[NBIN]; };
union FatLds   { NodeLds n; BinLds b; };

#define DECODE(J)                                                             \
    unsigned mx##J, my##J; int bn##J, rk##J;                                  \
    {                                                                         \
        int t = t0 + (J) * 1024 + tid;                                        \
        if (t < NT) {                                                         \
            int c, n1, n2;                                                    \
            if (fi) {                                                         \
                c  = qi[6LL * t];                                             \
                n1 = qi[6LL * t + 2];                                         \
                n2 = qi[6LL * t + 4];                                         \
            } else {                                                          \
                c  = qi[3LL * t];                                             \
                n1 = qi[3LL * t + 1];                                         \
                n2 = qi[3LL * t + 2];                                         \
            }                                                                 \
            float d1 = ldf(d1p, t, fb);                                       \
            float d2 = ldf(d2p, t, fb);                                       \
            float asym = fabsf(d1 - d2) / (fmaxf(d1, d2) + 1e-8f);            \
            unsigned qw = (unsigned)((1.0f + 0.3f * asym) * WQUANT + 0.5f);   \
            if (qw > 32767u) qw = 32767u;                                     \
            bn##J = c >> 6;                                                   \
            mx##J = (unsigned)n1 | (qw << 17);                                \
            my##J = (unsigned)n2 | ((unsigned)(c & 63) << 17);                \
            rk##J = atomicAdd(&L.b.h1[bn##J], 1);                             \
        } else { bn##J = -1; mx##J = 0u; my##J = 0u; rk##J = 0; }             \
    }

#define SCAT(J)                                                               \
    if (bn##J >= 0) {                                                         \
        int pos = L.b.gb[bn##J] + rk##J;                                      \
        if (pos < BINCAP)                                                     \
            binned[(size_t)bn##J * BINCAP + pos] = make_uint2(mx##J, my##J);  \
    }

__global__ __launch_bounds__(1024) void fused_nb_kernel(
        const void* __restrict__ h, const int* __restrict__ flags,
        const float* __restrict__ wu1f, const float* __restrict__ bf,
        __half* __restrict__ uh, __half* __restrict__ vh,
        const void* __restrict__ idxp,
        const void* __restrict__ d1p, const void* __restrict__ d2p,
        int* __restrict__ gcur, uint2* __restrict__ binned) {
    __shared__ FatLds L;
    int tid = threadIdx.x;
    int fb = flags[0];

    if (blockIdx.x < NCHK) {
        // ---------------- binA part ----------------
        int fi = flags[1];
        for (int i = tid; i < NBIN; i += 1024) L.b.h1[i] = 0;
        __syncthreads();
        int t0 = blockIdx.x * CHK;
        const int* qi = (const int*)idxp;         // int64: low words at even idx

        // phase 1: decode + histogram + rank, all state in NAMED scalars
        DECODE(0) DECODE(1) DECODE(2) DECODE(3)
        DECODE(4) DECODE(5) DECODE(6) DECODE(7)
        __syncthreads();
        for (int b = tid; b < NBIN; b += 1024) {  // reserve contiguous runs
            int n = L.b.h1[b];
            L.b.gb[b] = n ? atomicAdd(&gcur[b << 5], n) : 0;
        }
        __syncthreads();
        // phase 2: pure scatter writes at gb + rank
        SCAT(0) SCAT(1) SCAT(2) SCAT(3)
        SCAT(4) SCAT(5) SCAT(6) SCAT(7)
    } else {
        // ---------------- node part ----------------
        int base = (blockIdx.x - NCHK) * NPB;     // NN % 20 == 0
        for (int i = tid; i < HD * HD; i += 1024) {
            int o = i / HD, hh = i % HD;
            L.n.Ws[o * 49 + hh] = wu1f[i];
            L.n.Bs[o * 49 + hh] = bf[i];
        }
        for (int i = tid; i < NPB * HD; i += 1024)
            L.n.hs[i] = ldf(h, (long long)base * HD + i, fb);
        if (tid < NPB * 16) {  // zero the vh pad dims 48..63
            int ln = tid >> 4, o = HD + (tid & 15);
            vh[(size_t)(base + ln) * VS + o] = (__half)0.f;
        }
        __syncthreads();
        for (int i = tid; i < NPB * HD; i += 1024) {
            int ln = i / HD, o = i - ln * HD;
            const float* hr = L.n.hs + ln * HD;
            const float* wr = L.n.Ws + o * 49;
            const float* br = L.n.Bs + o * 49;
            float su = 0.f, sv = 0.f;
            #pragma unroll
            for (int k = 0; k < HD; ++k) { float hv = hr[k]; su += wr[k] * hv; sv += br[k] * hv; }
            int n = base + ln;
            uh[(size_t)n * HD + o] = __float2half(su);
            vh[(size_t)n * VS + o] = __float2half(sv);
        }
    }
}

// ---------------------------------------------------------------------------
// bin_accum (primary): one block per 64-center bin. Coalesced read of the
// bin's metas, LDS-atomic scatter into per-center LDS buckets (rows padded
// to 64 so the t+8+s probe stays in-row), then the proven per-wave accum
// (R5 form: 16 triples/trip, FOUR gathers issued back-to-back; validity
// selects give w=0/row-0 for tail slots): lane=(s 0..7, dg 0..7),
// single-line uint4 gathers of 8 fp16 dims, packed-fp16
// leaky(p)*w = (.505w)p + (.495w)|p|, drained to f32 per 16 triples.
// Fused residual + LayerNorm epilogue. 8 waves x 8 centers each.
// LDS = 36.6 KB -> 4 blocks/CU (32 waves/CU).
// NOTE (R3/R6 post-mortems): do NOT hand-pipeline (R3: 79->105us) and do
// NOT widen to 32-trip/8-gather (R6: 78.6->81.5us, VGPR 40, Occ -11pts).
// The 16-trip straight-line 4-gather block is a verified local optimum.
// ---------------------------------------------------------------------------
__global__ __launch_bounds__(512, 4) void bin_accum_kernel(
        const void* __restrict__ h, const int* __restrict__ flags,
        const __half* __restrict__ uh, const __half* __restrict__ vh,
        const int* __restrict__ gcur, const uint2* __restrict__ binned,
        const void* __restrict__ gamma, const void* __restrict__ beta,
        void* __restrict__ out) {
    __shared__ uint2 buckets[BINB][64];           // 32768 B, 56 slots used
    __shared__ int   cur[BINB];
    __shared__ float ucs[8][64];
    __shared__ float accs[8][HD];
    int tid = threadIdx.x, fb = flags[0];
    int bin = blockIdx.x;

    for (int i = tid; i < BINB; i += 512) cur[i] = 0;
    __syncthreads();

    int nm = gcur[bin << 5]; if (nm > BINCAP) nm = BINCAP;
    const uint2* bp = binned + (size_t)bin * BINCAP;
    for (int i = tid; i < nm; i += 512) {         // LDS bucket scatter
        uint2 m = bp[i];
        int cl = (m.y >> 17) & (BINB - 1);
        int r = atomicAdd(&cur[cl], 1);
        if (r < CAP) buckets[cl][r] = m;
    }
    __syncthreads();

    int wv = tid >> 6, lane = tid & 63;
    int s = lane >> 3, dg = lane & 7;
    const char* vb = (const char*)vh;
    size_t dgo = (size_t)dg * 16;
    float gv = (lane < HD) ? ldf(gamma, lane, fb) : 0.f;
    float bv = (lane < HD) ? ldf(beta, lane, fb) : 0.f;

    for (int ci = 0; ci < BINB / 8; ++ci) {       // 8 centers per wave
        int cl = wv * (BINB / 8) + ci;
        int n = bin * BINB + cl;
        if (n >= NN) continue;                    // last bin: tail centers

        int m = cur[cl]; if (m > CAP) m = CAP;
        float hval = (lane < HD) ? ldf(h, (long long)n * HD + lane, fb) : 0.f;
        float uval = (lane < HD) ? __half2float(uh[(size_t)n * HD + lane]) : 0.f;
        ucs[wv][lane] = uval;                     // wave-sync write->read
        hf2 uc4[4];
        #pragma unroll
        for (int j = 0; j < 4; ++j) {
            uc4[j].x = (_Float16)ucs[wv][dg * 8 + 2 * j];
            uc4[j].y = (_Float16)ucs[wv][dg * 8 + 2 * j + 1];
        }

        float accf[8] = {0.f, 0.f, 0.f, 0.f, 0.f, 0.f, 0.f, 0.f};
        for (int t = 0; t < m; t += 16) {
            uint2 m0 = buckets[cl][t + s];        // in padded row, LDS-safe
            uint2 m1 = buckets[cl][t + 8 + s];
            int v0 = (t + s) < m, v1 = (t + 8 + s) < m;
            unsigned a0 = v0 ? (m0.x & 0x1FFFFu) : 0u;
            unsigned b0 = v0 ? (m0.y & 0x1FFFFu) : 0u;
            float w0 = v0 ? (float)(m0.x >> 17) * WSCALE : 0.f;
            unsigned a1 = v1 ? (m1.x & 0x1FFFFu) : 0u;
            unsigned b1 = v1 ? (m1.y & 0x1FFFFu) : 0u;
            float w1 = v1 ? (float)(m1.x >> 17) * WSCALE : 0.f;
            V4H pa0, pb0, pa1, pb1;
            pa0.u = *(const uint4*)(vb + (size_t)a0 * 128 + dgo);
            pb0.u = *(const uint4*)(vb + (size_t)b0 * 128 + dgo);
            pa1.u = *(const uint4*)(vb + (size_t)a1 * 128 + dgo);
            pb1.u = *(const uint4*)(vb + (size_t)b1 * 128 + dgo);
            hf2 aw0 = splat2(0.505f * w0), bw0 = splat2(0.495f * w0);
            hf2 aw1 = splat2(0.505f * w1), bw1 = splat2(0.495f * w1);
            #pragma unroll
            for (int j = 0; j < 4; ++j) {
                hf2 p0 = pa0.h[j] + pb0.h[j] + uc4[j];
                hf2 acch = p0 * aw0 + habs2(p0) * bw0;
                hf2 p1 = pa1.h[j] + pb1.h[j] + uc4[j];
                acch += p1 * aw1 + habs2(p1) * bw1;
                accf[2 * j]     += (float)acch.x;
                accf[2 * j + 1] += (float)acch.y;
            }
        }

        // reduce across the 8 slot-copies (lane bits 3..5)
        #pragma unroll
        for (int j = 0; j < 8; ++j) {
            accf[j] += __shfl_xor(accf[j], 8, 64);
            accf[j] += __shfl_xor(accf[j], 16, 64);
            accf[j] += __shfl_xor(accf[j], 32, 64);
        }
        if (lane < 6) {                           // dims 0..47
            #pragma unroll
            for (int j = 0; j < 8; ++j) accs[wv][lane * 8 + j] = accf[j];
        }
        float av = (lane < HD) ? accs[wv][lane] : 0.f; // wave-sync

        float rnc = rsqrtf(fmaxf((float)m, 1.0f));
        float x = (lane < HD) ? (hval + av * rnc) : 0.f;
        float su = x, sq = x * x;
        #pragma unroll
        for (int o = 32; o; o >>= 1) {
            su += __shfl_xor(su, o, 64);
            sq += __shfl_xor(sq, o, 64);
        }
        float mu   = su * (1.0f / HD);
        float var  = sq * (1.0f / HD) - mu * mu;
        float rstd = rsqrtf(var + 1e-5f);
        if (lane < HD) {
            float r = (x - mu) * rstd * gv + bv;
            if (fb) ((__hip_bfloat16*)out)[(size_t)n * HD + lane] = __float2bfloat16(r);
            else    ((float*)out)[(size_t)n * HD + lane] = r;
        }
    }
}

// ---------------------------------------------------------------------------
// node (fallback only): u[n]=Wu1*h[n], v[n]=M*h[n].
// ---------------------------------------------------------------------------
__global__ __launch_bounds__(256) void node_kernel(
        const void* __restrict__ h, const int* __restrict__ flags,
        const float* __restrict__ wu1f, const float* __restrict__ bf,
        __half* __restrict__ uh, __half* __restrict__ vh) {
    __shared__ float Ws[HD * 49];
    __shared__ float Bs[HD * 49];
    __shared__ float hs[16 * HD];
    int tid = threadIdx.x;
    int fb = flags[0];
    for (int i = tid; i < HD * HD; i += 256) {
        int o = i / HD, hh = i % HD;
        Ws[o * 49 + hh] = wu1f[i];
        Bs[o * 49 + hh] = bf[i];
    }
    int base = blockIdx.x * 16;                   // NN % 16 == 0
    for (int i = tid; i < 16 * HD; i += 256)
        hs[i] = ldf(h, (long long)base * HD + i, fb);
    {   // zero the vh pad dims 48..63
        int ln = tid >> 4, o = HD + (tid & 15);
        vh[(size_t)(base + ln) * VS + o] = (__half)0.f;
    }
    __syncthreads();
    for (int i = tid; i < 16 * HD; i += 256) {
        int ln = i / HD, o = i - ln * HD;
        const float* hr = hs + ln * HD;
        const float* wr = Ws + o * 49;
        const float* br = Bs + o * 49;
        float su = 0.f, sv = 0.f;
        #pragma unroll
        for (int k = 0; k < HD; ++k) { float hv = hr[k]; su += wr[k] * hv; sv += br[k] * hv; }
        int n = base + ln;
        uh[(size_t)n * HD + o] = __float2half(su);
        vh[(size_t)n * VS + o] = __float2half(sv);
    }
}

// ---------------------------------------------------------------------------
// hist (fallback only): line-padded counters cnt[c<<4].
// ---------------------------------------------------------------------------
__global__ __launch_bounds__(256) void hist_kernel(const void* __restrict__ idxp,
                                                   const int* __restrict__ flags,
                                                   int* __restrict__ cnt) {
    int t = blockIdx.x * 256 + threadIdx.x;
    if (t >= NT) return;
    int c = flags[1] ? (int)((const long long*)idxp)[3LL * t]
                     : ((const int*)idxp)[3 * t];
    atomicAdd(&cnt[c << 4], 1);
}

// ---------------------------------------------------------------------------
// scans (fallback only): exclusive scan of cnt[i<<4] -> off[NN].
// ---------------------------------------------------------------------------
__global__ __launch_bounds__(1024) void scan_part(const int* __restrict__ cnt,
                                                  int* __restrict__ off,
                                                  int* __restrict__ bsum) {
    __shared__ int wsums[16];
    int tid = threadIdx.x, lane = tid & 63, wv = tid >> 6;
    int i = blockIdx.x * 1024 + tid;
    int x = (i < NN) ? cnt[i << 4] : 0;
    int vx = x;
    #pragma unroll
    for (int o = 1; o < 64; o <<= 1) {
        int y = __shfl_up(vx, o, 64);
        if (lane >= o) vx += y;
    }
    if (lane == 63) wsums[wv] = vx;
    __syncthreads();
    if (tid == 0) {
        int s = 0;
        #pragma unroll
        for (int k = 0; k < 16; ++k) { int t2 = wsums[k]; wsums[k] = s; s += t2; }
        bsum[blockIdx.x] = s;
    }
    __syncthreads();
    if (i < NN) off[i] = wsums[wv] + vx - x;
}

__global__ __launch_bounds__(1024) void scan_add(int* __restrict__ off,
                                                 const int* __restrict__ bsum) {
    int bid = blockIdx.x;
    int pre = 0;
    for (int k = 0; k < bid; ++k) pre += bsum[k];
    int i = bid * 1024 + threadIdx.x;
    if (i < NN) off[i] += pre;
}

// ---------------------------------------------------------------------------
// scatter (fallback only): meta = uint2{ n1 | qw<<17, n2 }.
// pos = atomicAdd(&off[c],1)  (off -> inclusive end)
// ---------------------------------------------------------------------------
__global__ __launch_bounds__(256) void scatter_kernel(
        const void* __restrict__ idxp,
        const void* __restrict__ d1p, const void* __restrict__ d2p,
        const int* __restrict__ flags, int* __restrict__ cur,
        uint2* __restrict__ sp) {
    int t = blockIdx.x * 256 + threadIdx.x;
    if (t >= NT) return;
    int fb = flags[0];
    int c, n1, n2;
    if (flags[1]) {
        const long long* q = (const long long*)idxp;
        c = (int)q[3LL * t]; n1 = (int)q[3LL * t + 1]; n2 = (int)q[3LL * t + 2];
    } else {
        const int* q = (const int*)idxp;
        c = q[3 * t]; n1 = q[3 * t + 1]; n2 = q[3 * t + 2];
    }
    float d1 = ldf(d1p, t, fb);
    float d2 = ldf(d2p, t, fb);
    float asym = fabsf(d1 - d2) / (fmaxf(d1, d2) + 1e-8f);
    unsigned int qw = (unsigned int)((1.0f + 0.3f * asym) * WQUANT + 0.5f);
    if (qw > 32767u) qw = 32767u;
    uint2 m = make_uint2((unsigned int)n1 | (qw << 17), (unsigned int)n2);
    int pos = atomicAdd(&cur[c], 1);
    sp[pos] = m;
}

// ---------------------------------------------------------------------------
// accum (fallback only): one wave per center, segment from off[].
// ---------------------------------------------------------------------------
__global__ __launch_bounds__(256) void accum_kernel(
        const void* __restrict__ h, const int* __restrict__ flags,
        const __half* __restrict__ uh, const __half* __restrict__ vh,
        const int* __restrict__ seg, const uint2* __restrict__ sp,
        const void* __restrict__ gamma, const void* __restrict__ beta,
        void* __restrict__ out) {
    __shared__ uint2 metas[4][64];
    __shared__ float ucs[4][64];
    __shared__ float accs[4][HD];
    int tid = threadIdx.x, fb = flags[0];
    int wv = tid >> 6, lane = tid & 63;
    int n = blockIdx.x * 4 + wv;                  // NN % 4 == 0

    float hval = (lane < HD) ? ldf(h, (long long)n * HD + lane, fb) : 0.f;
    float uval = (lane < HD) ? __half2float(uh[(size_t)n * HD + lane]) : 0.f;
    ucs[wv][lane] = uval;                         // wave-sync write->read

    int s = lane >> 3, dg = lane & 7;
    hf2 uc4[4];
    #pragma unroll
    for (int j = 0; j < 4; ++j) {
        uc4[j].x = (_Float16)ucs[wv][dg * 8 + 2 * j];
        uc4[j].y = (_Float16)ucs[wv][dg * 8 + 2 * j + 1];
    }

    int start = (n == 0) ? 0 : seg[n - 1];
    int end = seg[n];
    float accf[8] = {0.f, 0.f, 0.f, 0.f, 0.f, 0.f, 0.f, 0.f};
    const char* vb = (const char*)vh;
    size_t dgo = (size_t)dg * 16;

    for (int chunk = start; chunk < end; chunk += 64) {
        int m = end - chunk; if (m > 64) m = 64;
        if (lane < m) metas[wv][lane] = sp[chunk + lane];
        for (int t = 0; t < m; t += 16) {
            uint2 m0 = metas[wv][t + s];
            uint2 m1 = metas[wv][t + 8 + s];
            int v0 = (t + s) < m, v1 = (t + 8 + s) < m;
            unsigned a0 = v0 ? (m0.x & 0x1FFFFu) : 0u;
            unsigned b0 = v0 ? (m0.y & 0x1FFFFu) : 0u;
            float w0 = v0 ? (float)(m0.x >> 17) * WSCALE : 0.f;
            unsigned a1 = v1 ? (m1.x & 0x1FFFFu) : 0u;
            unsigned b1 = v1 ? (m1.y & 0x1FFFFu) : 0u;
            float w1 = v1 ? (float)(m1.x >> 17) * WSCALE : 0.f;
            V4H pa0, pb0, pa1, pb1;
            pa0.u = *(const uint4*)(vb + (size_t)a0 * 128 + dgo);
            pb0.u = *(const uint4*)(vb + (size_t)b0 * 128 + dgo);
            pa1.u = *(const uint4*)(vb + (size_t)a1 * 128 + dgo);
            pb1.u = *(const uint4*)(vb + (size_t)b1 * 128 + dgo);
            hf2 aw0 = splat2(0.505f * w0), bw0 = splat2(0.495f * w0);
            hf2 aw1 = splat2(0.505f * w1), bw1 = splat2(0.495f * w1);
            #pragma unroll
            for (int j = 0; j < 4; ++j) {
                hf2 p0 = pa0.h[j] + pb0.h[j] + uc4[j];
                hf2 acch = p0 * aw0 + habs2(p0) * bw0;
                hf2 p1 = pa1.h[j] + pb1.h[j] + uc4[j];
                acch += p1 * aw1 + habs2(p1) * bw1;
                accf[2 * j]     += (float)acch.x;
                accf[2 * j + 1] += (float)acch.y;
            }
        }
    }

    #pragma unroll
    for (int j = 0; j < 8; ++j) {
        accf[j] += __shfl_xor(accf[j], 8, 64);
        accf[j] += __shfl_xor(accf[j], 16, 64);
        accf[j] += __shfl_xor(accf[j], 32, 64);
    }
    if (lane < 6) {
        #pragma unroll
        for (int j = 0; j < 8; ++j) accs[wv][lane * 8 + j] = accf[j];
    }
    float av = (lane < HD) ? accs[wv][lane] : 0.f;

    float rnc = rsqrtf(fmaxf((float)(end - start), 1.0f));
    float x = (lane < HD) ? (hval + av * rnc) : 0.f;
    float su = x, sq = x * x;
    #pragma unroll
    for (int o = 32; o; o >>= 1) {
        su += __shfl_xor(su, o, 64);
        sq += __shfl_xor(sq, o, 64);
    }
    float mu   = su * (1.0f / HD);
    float var  = sq * (1.0f / HD) - mu * mu;
    float rstd = rsqrtf(var + 1e-5f);
    if (lane < HD) {
        float g  = ldf(gamma, lane, fb);
        float bb = ldf(beta, lane, fb);
        float r = (x - mu) * rstd * g + bb;
        if (fb) ((__hip_bfloat16*)out)[(size_t)n * HD + lane] = __float2bfloat16(r);
        else    ((float*)out)[(size_t)n * HD + lane] = r;
    }
}

extern "C" void kernel_launch(void* const* d_in, const int* in_sizes, int n_in,
                              void* d_out, int out_size, void* d_ws, size_t ws_size,
                              hipStream_t stream) {
    const void* h     = d_in[0];
    const void* idx   = d_in[1];
    const void* d1    = d_in[2];
    const void* d2    = d_in[3];
    const void* W3    = d_in[4];
    const void* Wu    = d_in[5];
    const void* gamma = d_in[6];
    const void* beta  = d_in[7];

    char* base  = (char*)d_ws;
    int*   flags = (int*)base;                              // 64 B
    float* wu1f  = (float*)(base + 64);                     // 2304 f
    float* bf    = wu1f + HD * HD;                          // 2304 f
    uintptr_t ua = (uintptr_t)(bf + HD * HD);
    __half* uh   = (__half*)((ua + 127) & ~(uintptr_t)127); // NN*48 fp16 (9.6 MB)
    __half* vh   = (__half*)((char*)uh + (size_t)NN * HD * 2); // NN*64 fp16 (12.8 MB)
    char*  after = (char*)vh + (size_t)NN * VS * 2;

    // Primary (coarse-bin) layout: gcur + binned after vh.
    int*   gcur = (int*)after;                              // NBIN*32 ints (200 KB)
    uintptr_t bna = (uintptr_t)(gcur + (size_t)NBIN * 32);
    uint2* binned = (uint2*)((bna + 127) & ~(uintptr_t)127); // NBIN*BINCAP*8 = 22.4 MB
    size_t need_primary = ((char*)(binned + (size_t)NBIN * BINCAP)) - base;

    // Fallback layout: cnt/off/bsum/sp after vh (R8 pipeline).
    int*   cnt  = (int*)after;                              // NN*16 ints (6.4 MB)
    int*   off  = (int*)(cnt + (size_t)NN * 16);            // NN
    int*   bsum = off + NN;                                 // NB (+pad)
    uintptr_t spa = (uintptr_t)(bsum + 256);
    uint2* sp   = (uint2*)((spa + 15) & ~(uintptr_t)15);    // NT uint2 (16 MB)

    prep_kernel<<<(HD * HD + 255) / 256, 256, 0, stream>>>(
        (const unsigned int*)h, (const unsigned int*)idx, flags, W3, Wu,
        wu1f, bf, gcur);

    if (ws_size >= need_primary) {
        // ---- coarse-bin path: fused (node || binA) + bucket/accum ----
        fused_nb_kernel<<<FATGRID, 1024, 0, stream>>>(
            h, flags, wu1f, bf, uh, vh, idx, d1, d2, gcur, binned);
        bin_accum_kernel<<<NBIN, 512, 0, stream>>>(h, flags, uh, vh, gcur, binned,
                                                   gamma, beta, d_out);
    } else {
        // ---- fallback: hist + scan + sorted scatter (R8 pipeline) ----
        node_kernel<<<NN / 16, 256, 0, stream>>>(h, flags, wu1f, bf, uh, vh);
        hipMemsetAsync(cnt, 0, (size_t)NN * 16 * sizeof(int), stream);
        hist_kernel<<<NBH, 256, 0, stream>>>(idx, flags, cnt);
        scan_part<<<NB, 1024, 0, stream>>>(cnt, off, bsum);
        scan_add<<<NB, 1024, 0, stream>>>(off, bsum);
        scatter_kernel<<<(NT + 255) / 256, 256, 0, stream>>>(
            idx, d1, d2, flags, off, sp);
        accum_kernel<<<NN / 4, 256, 0, stream>>>(h, flags, uh, vh, off, sp,
                                                 gamma, beta, d_out);
    }
}